// Round 1
// baseline (1740.091 us; speedup 1.0000x reference)
//
#include <hip/hip_runtime.h>
#include <hip/hip_bf16.h>
#include <math.h>

#define HIDDEN 1280
#define HEADS 16
#define HD 80           // head dim
#define HALF 40
#define BB 2
#define NN 2048
#define MROWS (BB * NN) // 4096

// ---------------------------------------------------------------------------
// Generic fp32 GEMM with bias: C[M,N] = A[M,K] @ B[K,N] + bias[N]
// 128x128 block tile, 16 k-tile, 8x8 per-thread register tile, 256 threads.
// M,N,K must be multiples of 128/128/16 (true for all calls here).
// ---------------------------------------------------------------------------
#define GBM 128
#define GBN 128
#define GBK 16
#define GTM 8
#define GTN 8

__global__ __launch_bounds__(256) void gemm_bias_kernel(
    const float* __restrict__ A, const float* __restrict__ B,
    const float* __restrict__ bias, float* __restrict__ C,
    int M, int N, int K)
{
    __shared__ float s_a[GBK][GBM + 4];
    __shared__ float s_b[GBK][GBN + 4];

    const int tid = threadIdx.x;
    const int bn = blockIdx.x;
    const int bm = blockIdx.y;
    const int tx = tid & 15;
    const int ty = tid >> 4;
    const int row0 = bm * GBM;
    const int col0 = bn * GBN;

    float acc[GTM][GTN] = {};

    for (int k0 = 0; k0 < K; k0 += GBK) {
        // A tile: 128x16 = 512 float4s, 2 per thread (store transposed to LDS)
        #pragma unroll
        for (int i = 0; i < 2; ++i) {
            int idx = tid + i * 256;        // float4 index
            int ar = idx >> 2;              // 4 float4 per row
            int ak = (idx & 3) * 4;
            float4 av = *(const float4*)(A + (size_t)(row0 + ar) * K + k0 + ak);
            s_a[ak + 0][ar] = av.x;
            s_a[ak + 1][ar] = av.y;
            s_a[ak + 2][ar] = av.z;
            s_a[ak + 3][ar] = av.w;
        }
        // B tile: 16x128 = 512 float4s, 2 per thread
        #pragma unroll
        for (int i = 0; i < 2; ++i) {
            int idx = tid + i * 256;
            int br = idx >> 5;              // 32 float4 per row
            int bc = (idx & 31) * 4;
            *(float4*)(&s_b[br][bc]) =
                *(const float4*)(B + (size_t)(k0 + br) * N + col0 + bc);
        }
        __syncthreads();

        #pragma unroll
        for (int kk = 0; kk < GBK; ++kk) {
            float a_frag[GTM], b_frag[GTN];
            #pragma unroll
            for (int i = 0; i < GTM; i += 4)
                *(float4*)(&a_frag[i]) = *(const float4*)(&s_a[kk][ty * GTM + i]);
            #pragma unroll
            for (int j = 0; j < GTN; j += 4)
                *(float4*)(&b_frag[j]) = *(const float4*)(&s_b[kk][tx * GTN + j]);
            #pragma unroll
            for (int i = 0; i < GTM; ++i)
                #pragma unroll
                for (int j = 0; j < GTN; ++j)
                    acc[i][j] += a_frag[i] * b_frag[j];
        }
        __syncthreads();
    }

    #pragma unroll
    for (int i = 0; i < GTM; ++i) {
        int r = row0 + ty * GTM + i;
        #pragma unroll
        for (int j = 0; j < GTN; j += 4) {
            int c = col0 + tx * GTN + j;
            float4 bv = *(const float4*)(bias + c);
            float4 o;
            o.x = acc[i][j + 0] + bv.x;
            o.y = acc[i][j + 1] + bv.y;
            o.z = acc[i][j + 2] + bv.z;
            o.w = acc[i][j + 3] + bv.w;
            *(float4*)(C + (size_t)r * N + c) = o;
        }
    }
}

// ---------------------------------------------------------------------------
// RoPE in-place on qkv buffer, layout (b, n, 3, H, 80). Applies to q (s=0)
// and k (s=1). One thread per (b,n,h,d<40) pair.
// ---------------------------------------------------------------------------
__global__ __launch_bounds__(256) void rope_kernel(
    float* __restrict__ qkv, const float* __restrict__ cos_t,
    const float* __restrict__ sin_t)
{
    int idx = blockIdx.x * blockDim.x + threadIdx.x;
    int d = idx % HALF;
    int h = (idx / HALF) % HEADS;
    int n = (idx / (HALF * HEADS)) % NN;
    int b = idx / (HALF * HEADS * NN);
    if (b >= BB) return;

    float c0 = cos_t[n * HD + d];
    float c1 = cos_t[n * HD + d + HALF];
    float s0 = sin_t[n * HD + d];
    float s1 = sin_t[n * HD + d + HALF];

    #pragma unroll
    for (int s = 0; s < 2; ++s) {
        size_t base = ((size_t)(b * NN + n) * 3 + s) * HIDDEN + h * HD;
        float x0 = qkv[base + d];
        float x1 = qkv[base + d + HALF];
        qkv[base + d]        = x0 * c1 * 0.0f + x0 * c0 - x1 * s0; // x0*cos - x1*sin
        qkv[base + d + HALF] = x1 * c1 + x0 * s1;                  // x1*cos + x0*sin
    }
}

// ---------------------------------------------------------------------------
// Flash-style attention, fp32. Block = 256 threads = 64 q-rows x 4 lanes.
// Each block: one (b, h, 64-row q tile). Iterates 64-key K/V tiles with
// online softmax. Q row kept in registers (pre-scaled). Output written
// directly in (b, n, HIDDEN) layout.
// ---------------------------------------------------------------------------
#define AT_BR 64
#define AT_BC 64

__global__ __launch_bounds__(256) void attn_kernel(
    const float* __restrict__ qkv, float* __restrict__ out)
{
    __shared__ float k_s[AT_BC][HD];          // 20 KB
    __shared__ float v_s[AT_BC][HD];          // 20 KB
    __shared__ float p_s[AT_BR][AT_BC + 4];   // 17 KB

    const int tid = threadIdx.x;
    const int r = tid >> 2;      // local q row 0..63
    const int c = tid & 3;       // 0..3, owns output dims [c*20, c*20+20)
    const int qt = blockIdx.x;   // q tile
    const int h  = blockIdx.y;
    const int b  = blockIdx.z;
    const int q0 = qt * AT_BR;

    const float scale = 0.11180339887498949f; // 1/sqrt(80)

    // Q row into registers, pre-scaled
    float q_reg[HD];
    {
        size_t qbase = ((size_t)(b * NN + q0 + r) * 3 + 0) * HIDDEN + h * HD;
        #pragma unroll
        for (int d = 0; d < HD; d += 4) {
            float4 v = *(const float4*)(qkv + qbase + d);
            q_reg[d + 0] = v.x * scale;
            q_reg[d + 1] = v.y * scale;
            q_reg[d + 2] = v.z * scale;
            q_reg[d + 3] = v.w * scale;
        }
    }

    float m = -INFINITY;
    float l = 0.0f;
    float o_acc[20] = {};

    for (int t = 0; t < NN; t += AT_BC) {
        __syncthreads();  // protect LDS tiles from previous iteration's readers
        // load K and V tiles: 64 rows x 80 floats = 1280 float4 each, 5/thread
        #pragma unroll
        for (int i = 0; i < 5; ++i) {
            int idx = tid + i * 256;
            int row = idx / 20;
            int col = (idx % 20) * 4;
            size_t kbase = ((size_t)(b * NN + t + row) * 3 + 1) * HIDDEN + h * HD + col;
            size_t vbase = ((size_t)(b * NN + t + row) * 3 + 2) * HIDDEN + h * HD + col;
            *(float4*)(&k_s[row][col]) = *(const float4*)(qkv + kbase);
            *(float4*)(&v_s[row][col]) = *(const float4*)(qkv + vbase);
        }
        __syncthreads();

        // scores for my 16 keys: j = jj*4 + c
        float sv[16];
        #pragma unroll
        for (int jj = 0; jj < 16; ++jj) {
            int j = jj * 4 + c;
            float acc = 0.0f;
            #pragma unroll
            for (int d = 0; d < HD; d += 4) {
                float4 kv = *(const float4*)(&k_s[j][d]);
                acc += q_reg[d + 0] * kv.x;
                acc += q_reg[d + 1] * kv.y;
                acc += q_reg[d + 2] * kv.z;
                acc += q_reg[d + 3] * kv.w;
            }
            sv[jj] = acc;
        }

        // online softmax (4 lanes per row share state via shfl width 4)
        float tmax = sv[0];
        #pragma unroll
        for (int jj = 1; jj < 16; ++jj) tmax = fmaxf(tmax, sv[jj]);
        tmax = fmaxf(tmax, __shfl_xor(tmax, 1, 4));
        tmax = fmaxf(tmax, __shfl_xor(tmax, 2, 4));
        float m_new = fmaxf(m, tmax);
        float alpha = __expf(m - m_new);
        float tsum = 0.0f;
        #pragma unroll
        for (int jj = 0; jj < 16; ++jj) {
            float p = __expf(sv[jj] - m_new);
            tsum += p;
            p_s[r][jj * 4 + c] = p;
        }
        tsum += __shfl_xor(tsum, 1, 4);
        tsum += __shfl_xor(tsum, 2, 4);
        l = l * alpha + tsum;
        m = m_new;

        // O update: O = O*alpha + P @ V   (this row's p_s written by same wave)
        #pragma unroll
        for (int d = 0; d < 20; ++d) o_acc[d] *= alpha;
        for (int j = 0; j < AT_BC; ++j) {
            float p = p_s[r][j];
            #pragma unroll
            for (int d = 0; d < 20; d += 4) {
                float4 vv = *(const float4*)(&v_s[j][c * 20 + d]);
                o_acc[d + 0] += p * vv.x;
                o_acc[d + 1] += p * vv.y;
                o_acc[d + 2] += p * vv.z;
                o_acc[d + 3] += p * vv.w;
            }
        }
    }

    const float inv_l = 1.0f / l;
    size_t obase = ((size_t)b * NN + q0 + r) * HIDDEN + h * HD + c * 20;
    #pragma unroll
    for (int d = 0; d < 20; d += 4) {
        float4 o;
        o.x = o_acc[d + 0] * inv_l;
        o.y = o_acc[d + 1] * inv_l;
        o.z = o_acc[d + 2] * inv_l;
        o.w = o_acc[d + 3] * inv_l;
        *(float4*)(out + obase + d) = o;
    }
}

// ---------------------------------------------------------------------------
extern "C" void kernel_launch(void* const* d_in, const int* in_sizes, int n_in,
                              void* d_out, int out_size, void* d_ws, size_t ws_size,
                              hipStream_t stream)
{
    const float* x      = (const float*)d_in[0];
    const float* cos_t  = (const float*)d_in[1];
    const float* sin_t  = (const float*)d_in[2];
    const float* qkv_w  = (const float*)d_in[3];
    const float* qkv_b  = (const float*)d_in[4];
    const float* proj_w = (const float*)d_in[5];
    const float* proj_b = (const float*)d_in[6];
    float* out = (float*)d_out;

    float* qkv      = (float*)d_ws;                      // 4096 x 3840 = 63 MB
    float* attn_out = qkv + (size_t)MROWS * 3 * HIDDEN;  // 4096 x 1280 = 21 MB

    // 1) qkv = x @ qkv_w + qkv_b      (4096x1280 @ 1280x3840)
    gemm_bias_kernel<<<dim3(3 * HIDDEN / GBN, MROWS / GBM), 256, 0, stream>>>(
        x, qkv_w, qkv_b, qkv, MROWS, 3 * HIDDEN, HIDDEN);

    // 2) RoPE in place on q,k
    int rope_threads = BB * NN * HEADS * HALF;  // 2,621,440
    rope_kernel<<<rope_threads / 256, 256, 0, stream>>>(qkv, cos_t, sin_t);

    // 3) attention -> attn_out (b, n, HIDDEN)
    attn_kernel<<<dim3(NN / AT_BR, HEADS, BB), 256, 0, stream>>>(qkv, attn_out);

    // 4) out = attn_out @ proj_w + proj_b   (4096x1280 @ 1280x1280)
    gemm_bias_kernel<<<dim3(HIDDEN / GBN, MROWS / GBM), 256, 0, stream>>>(
        attn_out, proj_w, proj_b, out, MROWS, HIDDEN, HIDDEN);
}

// Round 2
// 1371.909 us; speedup vs baseline: 1.2684x; 1.2684x over previous
//
#include <hip/hip_runtime.h>
#include <hip/hip_bf16.h>
#include <math.h>

#define HIDDEN 1280
#define HEADS 16
#define HD 80           // head dim
#define HALF 40
#define BB 2
#define NN 2048
#define MROWS (BB * NN) // 4096

typedef __attribute__((ext_vector_type(8))) __bf16 bf16x8;
typedef __attribute__((ext_vector_type(4))) float f32x4;

// Split fp32 into bf16 hi + bf16 lo (hi+lo carries ~16 mantissa bits).
__device__ __forceinline__ void split2(float x, ushort& hi, ushort& lo) {
    __hip_bfloat16 h = __float2bfloat16(x);
    float r = x - __bfloat162float(h);
    __hip_bfloat16 l = __float2bfloat16(r);
    hi = __builtin_bit_cast(ushort, h);
    lo = __builtin_bit_cast(ushort, l);
}

// ---------------------------------------------------------------------------
// Elementwise split: fp32 [n] -> bf16 hi[n], lo[n]. 4 elems/thread.
// ---------------------------------------------------------------------------
__global__ __launch_bounds__(256) void split_kernel(
    const float* __restrict__ in, ushort* __restrict__ hi,
    ushort* __restrict__ lo, int n4)
{
    int i = blockIdx.x * 256 + threadIdx.x;
    if (i >= n4) return;
    float4 v = ((const float4*)in)[i];
    ushort4 h, l;
    split2(v.x, h.x, l.x);
    split2(v.y, h.y, l.y);
    split2(v.z, h.z, l.z);
    split2(v.w, h.w, l.w);
    ((ushort4*)hi)[i] = h;
    ((ushort4*)lo)[i] = l;
}

// ---------------------------------------------------------------------------
// Transpose + split: W[K][N] fp32 -> WT_hi[N][K], WT_lo[N][K] bf16.
// 32x32 LDS tile, coalesced both directions. Grid (N/32, K/32).
// ---------------------------------------------------------------------------
__global__ __launch_bounds__(256) void tsplit_kernel(
    const float* __restrict__ W, ushort* __restrict__ Thi,
    ushort* __restrict__ Tlo, int K, int N)
{
    __shared__ float s[32][33];
    const int n0 = blockIdx.x * 32;
    const int k0 = blockIdx.y * 32;
    {
        int tn = threadIdx.x & 31, tk = threadIdx.x >> 5; // tk 0..7
        #pragma unroll
        for (int i = 0; i < 4; ++i)
            s[tk + i * 8][tn] = W[(size_t)(k0 + tk + i * 8) * N + n0 + tn];
    }
    __syncthreads();
    {
        int tk = threadIdx.x & 31, tn = threadIdx.x >> 5; // tn 0..7
        #pragma unroll
        for (int i = 0; i < 4; ++i) {
            float v = s[tk][tn + i * 8];
            ushort h, l;
            split2(v, h, l);
            size_t o = (size_t)(n0 + tn + i * 8) * K + k0 + tk;
            Thi[o] = h;
            Tlo[o] = l;
        }
    }
}

// ---------------------------------------------------------------------------
// bf16x3 MFMA GEMM: C[M,N] = (Ahi+Alo)[M,K] @ (Bhi+Blo)[N,K]^T + bias[N]
// A and BT are both [rows][K] with K contiguous (bf16). 128x128 tile,
// BK=32, 256 threads = 4 waves (2x2), each wave 64x64 = 4x4 MFMA tiles.
// 3 MFMAs per tile: Al*Bh + Ah*Bl + Ah*Bh  (error ~2^-18).
// ---------------------------------------------------------------------------
#define BM 128
#define BN 128
#define BK 32

__global__ __launch_bounds__(256) void gemm_bf16x3_kernel(
    const ushort* __restrict__ Ahi, const ushort* __restrict__ Alo,
    const ushort* __restrict__ Bhi, const ushort* __restrict__ Blo,
    const float* __restrict__ bias, float* __restrict__ C,
    int M, int N, int K)
{
    // 4 tiles (Ahi, Alo, Bhi, Blo), each 128 rows x 32 bf16 = 8 KB -> 32 KB
    __shared__ __align__(16) ushort lds[4 * 128 * 32];

    const int tid = threadIdx.x;
    const int wid = tid >> 6;
    const int lane = tid & 63;
    const int col0 = blockIdx.x * BN;
    const int row0 = blockIdx.y * BM;
    const int wy = wid >> 1, wx = wid & 1;

    // staging assignment: wave w stages tile w
    const ushort* src = (wid == 0) ? Ahi : (wid == 1) ? Alo : (wid == 2) ? Bhi : Blo;
    const int srow = (wid < 2) ? row0 : col0;
    ushort* lbase = lds + wid * 4096;
    const int lrow = lane >> 2;   // 0..15 (16 rows per 1 KB wave-load)
    const int lchunk = lane & 3;  // 4 x 16B chunks per 64B row

    f32x4 acc[4][4] = {};

    for (int k0 = 0; k0 < K; k0 += BK) {
        __syncthreads();
        {
            const ushort* g0 = src + (size_t)(srow + lrow) * K + k0 + lchunk * 8;
            ushort* l0 = lbase + lane * 8;
            #pragma unroll
            for (int t = 0; t < 8; ++t) {
                __builtin_amdgcn_global_load_lds(
                    (const __attribute__((address_space(1))) unsigned int*)(g0 + (size_t)t * 16 * K),
                    (__attribute__((address_space(3))) unsigned int*)(l0 + t * 512),
                    16, 0, 0);
            }
        }
        __syncthreads();

        const int q = lane >> 4;   // quad: k-offset q*8
        const int r = lane & 15;   // row/col within 16-tile
        bf16x8 ah[4], al[4], bh[4], bl[4];
        #pragma unroll
        for (int i = 0; i < 4; ++i) {
            int arow = wy * 64 + i * 16 + r;
            ah[i] = *(const bf16x8*)(lds + 0 * 4096 + arow * 32 + q * 8);
            al[i] = *(const bf16x8*)(lds + 1 * 4096 + arow * 32 + q * 8);
            int brow = wx * 64 + i * 16 + r;
            bh[i] = *(const bf16x8*)(lds + 2 * 4096 + brow * 32 + q * 8);
            bl[i] = *(const bf16x8*)(lds + 3 * 4096 + brow * 32 + q * 8);
        }
        #pragma unroll
        for (int i = 0; i < 4; ++i) {
            #pragma unroll
            for (int j = 0; j < 4; ++j) {
                acc[i][j] = __builtin_amdgcn_mfma_f32_16x16x32_bf16(al[i], bh[j], acc[i][j], 0, 0, 0);
                acc[i][j] = __builtin_amdgcn_mfma_f32_16x16x32_bf16(ah[i], bl[j], acc[i][j], 0, 0, 0);
                acc[i][j] = __builtin_amdgcn_mfma_f32_16x16x32_bf16(ah[i], bh[j], acc[i][j], 0, 0, 0);
            }
        }
    }

    // epilogue: C/D layout col=lane&15, row=quad*4+reg
    const int q = lane >> 4, r = lane & 15;
    #pragma unroll
    for (int i = 0; i < 4; ++i) {
        #pragma unroll
        for (int j = 0; j < 4; ++j) {
            int col = col0 + wx * 64 + j * 16 + r;
            float b = bias[col];
            #pragma unroll
            for (int v = 0; v < 4; ++v) {
                int row = row0 + wy * 64 + i * 16 + q * 4 + v;
                C[(size_t)row * N + col] = acc[i][j][v] + b;
            }
        }
    }
}

// ---------------------------------------------------------------------------
// RoPE in-place on qkv buffer, layout (b, n, 3, H, 80). Applies to q,k.
// ---------------------------------------------------------------------------
__global__ __launch_bounds__(256) void rope_kernel(
    float* __restrict__ qkv, const float* __restrict__ cos_t,
    const float* __restrict__ sin_t)
{
    int idx = blockIdx.x * blockDim.x + threadIdx.x;
    int d = idx % HALF;
    int h = (idx / HALF) % HEADS;
    int n = (idx / (HALF * HEADS)) % NN;
    int b = idx / (HALF * HEADS * NN);
    if (b >= BB) return;

    float c0 = cos_t[n * HD + d];
    float c1 = cos_t[n * HD + d + HALF];
    float s0 = sin_t[n * HD + d];
    float s1 = sin_t[n * HD + d + HALF];

    #pragma unroll
    for (int s = 0; s < 2; ++s) {
        size_t base = ((size_t)(b * NN + n) * 3 + s) * HIDDEN + h * HD;
        float x0 = qkv[base + d];
        float x1 = qkv[base + d + HALF];
        qkv[base + d]        = x0 * c0 - x1 * s0;
        qkv[base + d + HALF] = x1 * c1 + x0 * s1;
    }
}

// ---------------------------------------------------------------------------
// Flash-style attention, fp32 compute. Writes output pre-split to bf16
// hi/lo (for the bf16x3 proj GEMM). Block = 64 q-rows x 4 lanes.
// ---------------------------------------------------------------------------
#define AT_BR 64
#define AT_BC 64

__global__ __launch_bounds__(256) void attn_kernel(
    const float* __restrict__ qkv, ushort* __restrict__ ao_hi,
    ushort* __restrict__ ao_lo)
{
    __shared__ float k_s[AT_BC][HD];
    __shared__ float v_s[AT_BC][HD];
    __shared__ float p_s[AT_BR][AT_BC + 4];

    const int tid = threadIdx.x;
    const int r = tid >> 2;      // local q row 0..63
    const int c = tid & 3;       // owns output dims [c*20, c*20+20)
    const int qt = blockIdx.x;
    const int h  = blockIdx.y;
    const int b  = blockIdx.z;
    const int q0 = qt * AT_BR;

    const float scale = 0.11180339887498949f; // 1/sqrt(80)

    float q_reg[HD];
    {
        size_t qbase = ((size_t)(b * NN + q0 + r) * 3 + 0) * HIDDEN + h * HD;
        #pragma unroll
        for (int d = 0; d < HD; d += 4) {
            float4 v = *(const float4*)(qkv + qbase + d);
            q_reg[d + 0] = v.x * scale;
            q_reg[d + 1] = v.y * scale;
            q_reg[d + 2] = v.z * scale;
            q_reg[d + 3] = v.w * scale;
        }
    }

    float m = -INFINITY;
    float l = 0.0f;
    float o_acc[20] = {};

    for (int t = 0; t < NN; t += AT_BC) {
        __syncthreads();
        #pragma unroll
        for (int i = 0; i < 5; ++i) {
            int idx = tid + i * 256;
            int row = idx / 20;
            int col = (idx % 20) * 4;
            size_t kbase = ((size_t)(b * NN + t + row) * 3 + 1) * HIDDEN + h * HD + col;
            size_t vbase = ((size_t)(b * NN + t + row) * 3 + 2) * HIDDEN + h * HD + col;
            *(float4*)(&k_s[row][col]) = *(const float4*)(qkv + kbase);
            *(float4*)(&v_s[row][col]) = *(const float4*)(qkv + vbase);
        }
        __syncthreads();

        float sv[16];
        #pragma unroll
        for (int jj = 0; jj < 16; ++jj) {
            int j = jj * 4 + c;
            float acc = 0.0f;
            #pragma unroll
            for (int d = 0; d < HD; d += 4) {
                float4 kv = *(const float4*)(&k_s[j][d]);
                acc += q_reg[d + 0] * kv.x;
                acc += q_reg[d + 1] * kv.y;
                acc += q_reg[d + 2] * kv.z;
                acc += q_reg[d + 3] * kv.w;
            }
            sv[jj] = acc;
        }

        float tmax = sv[0];
        #pragma unroll
        for (int jj = 1; jj < 16; ++jj) tmax = fmaxf(tmax, sv[jj]);
        tmax = fmaxf(tmax, __shfl_xor(tmax, 1, 4));
        tmax = fmaxf(tmax, __shfl_xor(tmax, 2, 4));
        float m_new = fmaxf(m, tmax);
        float alpha = __expf(m - m_new);
        float tsum = 0.0f;
        #pragma unroll
        for (int jj = 0; jj < 16; ++jj) {
            float p = __expf(sv[jj] - m_new);
            tsum += p;
            p_s[r][jj * 4 + c] = p;
        }
        tsum += __shfl_xor(tsum, 1, 4);
        tsum += __shfl_xor(tsum, 2, 4);
        l = l * alpha + tsum;
        m = m_new;

        #pragma unroll
        for (int d = 0; d < 20; ++d) o_acc[d] *= alpha;
        for (int j = 0; j < AT_BC; ++j) {
            float p = p_s[r][j];
            #pragma unroll
            for (int d = 0; d < 20; d += 4) {
                float4 vv = *(const float4*)(&v_s[j][c * 20 + d]);
                o_acc[d + 0] += p * vv.x;
                o_acc[d + 1] += p * vv.y;
                o_acc[d + 2] += p * vv.z;
                o_acc[d + 3] += p * vv.w;
            }
        }
    }

    const float inv_l = 1.0f / l;
    size_t obase = ((size_t)(b * NN + q0 + r)) * HIDDEN + h * HD + c * 20;
    #pragma unroll
    for (int d = 0; d < 20; ++d) {
        float v = o_acc[d] * inv_l;
        ushort hh, ll;
        split2(v, hh, ll);
        ao_hi[obase + d] = hh;
        ao_lo[obase + d] = ll;
    }
}

// ---------------------------------------------------------------------------
extern "C" void kernel_launch(void* const* d_in, const int* in_sizes, int n_in,
                              void* d_out, int out_size, void* d_ws, size_t ws_size,
                              hipStream_t stream)
{
    const float* x      = (const float*)d_in[0];
    const float* cos_t  = (const float*)d_in[1];
    const float* sin_t  = (const float*)d_in[2];
    const float* qkv_w  = (const float*)d_in[3];
    const float* qkv_b  = (const float*)d_in[4];
    const float* proj_w = (const float*)d_in[5];
    const float* proj_b = (const float*)d_in[6];
    float* out = (float*)d_out;

    char* ws = (char*)d_ws;
    // layout (bytes):
    //   qkv fp32:           0 .. 62,914,560
    //   wT_hi bf16:  62,914,560 (3840x1280)   [reused for projT_hi]
    //   wT_lo bf16:  72,744,960               [reused for projT_lo]
    //   a_hi  bf16:  82,575,360 (4096x1280)   [x split, then attn-out split]
    //   a_lo  bf16:  93,061,120
    float*  qkv   = (float*)ws;
    ushort* wT_hi = (ushort*)(ws + 62914560);
    ushort* wT_lo = (ushort*)(ws + 72744960);
    ushort* a_hi  = (ushort*)(ws + 82575360);
    ushort* a_lo  = (ushort*)(ws + 93061120);

    // 1) split x into bf16 hi/lo
    split_kernel<<<(MROWS * HIDDEN / 4 + 255) / 256, 256, 0, stream>>>(
        x, a_hi, a_lo, MROWS * HIDDEN / 4);

    // 2) transpose+split qkv_w [1280][3840] -> [3840][1280] hi/lo
    tsplit_kernel<<<dim3(3 * HIDDEN / 32, HIDDEN / 32), 256, 0, stream>>>(
        qkv_w, wT_hi, wT_lo, HIDDEN, 3 * HIDDEN);

    // 3) qkv = x @ qkv_w + qkv_b   (bf16x3 MFMA)
    gemm_bf16x3_kernel<<<dim3(3 * HIDDEN / BN, MROWS / BM), 256, 0, stream>>>(
        a_hi, a_lo, wT_hi, wT_lo, qkv_b, qkv, MROWS, 3 * HIDDEN, HIDDEN);

    // 4) RoPE in place
    rope_kernel<<<BB * NN * HEADS * HALF / 256, 256, 0, stream>>>(qkv, cos_t, sin_t);

    // 5) attention -> pre-split bf16 hi/lo output (reuses x-split buffers)
    attn_kernel<<<dim3(NN / AT_BR, HEADS, BB), 256, 0, stream>>>(qkv, a_hi, a_lo);

    // 6) transpose+split proj_w [1280][1280]
    tsplit_kernel<<<dim3(HIDDEN / 32, HIDDEN / 32), 256, 0, stream>>>(
        proj_w, wT_hi, wT_lo, HIDDEN, HIDDEN);

    // 7) out = attn_out @ proj_w + proj_b   (bf16x3 MFMA)
    gemm_bf16x3_kernel<<<dim3(HIDDEN / BN, MROWS / BM), 256, 0, stream>>>(
        a_hi, a_lo, wT_hi, wT_lo, proj_b, out, MROWS, HIDDEN, HIDDEN);
}

// Round 3
// 527.280 us; speedup vs baseline: 3.3001x; 2.6019x over previous
//
#include <hip/hip_runtime.h>
#include <hip/hip_bf16.h>
#include <math.h>

#define HIDDEN 1280
#define HEADS 16
#define HD 80           // head dim
#define HALF 40
#define BB 2
#define NN 2048
#define MROWS (BB * NN) // 4096
#define SM_SCALE 0.11180339887498949f  // 1/sqrt(80)

typedef __attribute__((ext_vector_type(8))) __bf16 bf16x8;
typedef __attribute__((ext_vector_type(4))) float f32x4;

// Split fp32 into bf16 hi + bf16 lo (hi+lo carries ~16 mantissa bits).
__device__ __forceinline__ void split2(float x, ushort& hi, ushort& lo) {
    __hip_bfloat16 h = __float2bfloat16(x);
    float r = x - __bfloat162float(h);
    __hip_bfloat16 l = __float2bfloat16(r);
    hi = __builtin_bit_cast(ushort, h);
    lo = __builtin_bit_cast(ushort, l);
}

// ---------------------------------------------------------------------------
// Elementwise split: fp32 [n] -> bf16 hi[n], lo[n]. 4 elems/thread.
// ---------------------------------------------------------------------------
__global__ __launch_bounds__(256) void split_kernel(
    const float* __restrict__ in, ushort* __restrict__ hi,
    ushort* __restrict__ lo, int n4)
{
    int i = blockIdx.x * 256 + threadIdx.x;
    if (i >= n4) return;
    float4 v = ((const float4*)in)[i];
    ushort4 h, l;
    split2(v.x, h.x, l.x);
    split2(v.y, h.y, l.y);
    split2(v.z, h.z, l.z);
    split2(v.w, h.w, l.w);
    ((ushort4*)hi)[i] = h;
    ((ushort4*)lo)[i] = l;
}

// ---------------------------------------------------------------------------
// Transpose + split: W[K][N] fp32 -> WT_hi[N][K], WT_lo[N][K] bf16.
// ---------------------------------------------------------------------------
__global__ __launch_bounds__(256) void tsplit_kernel(
    const float* __restrict__ W, ushort* __restrict__ Thi,
    ushort* __restrict__ Tlo, int K, int N)
{
    __shared__ float s[32][33];
    const int n0 = blockIdx.x * 32;
    const int k0 = blockIdx.y * 32;
    {
        int tn = threadIdx.x & 31, tk = threadIdx.x >> 5;
        #pragma unroll
        for (int i = 0; i < 4; ++i)
            s[tk + i * 8][tn] = W[(size_t)(k0 + tk + i * 8) * N + n0 + tn];
    }
    __syncthreads();
    {
        int tk = threadIdx.x & 31, tn = threadIdx.x >> 5;
        #pragma unroll
        for (int i = 0; i < 4; ++i) {
            float v = s[tk][tn + i * 8];
            ushort h, l;
            split2(v, h, l);
            size_t o = (size_t)(n0 + tn + i * 8) * K + k0 + tk;
            Thi[o] = h;
            Tlo[o] = l;
        }
    }
}

// ---------------------------------------------------------------------------
// bf16x3 MFMA GEMM: C[M,N] = (Ahi+Alo)[M,K] @ (Bhi+Blo)[N,K]^T + bias[N]
// ---------------------------------------------------------------------------
#define BM 128
#define BN 128
#define BK 32

__global__ __launch_bounds__(256) void gemm_bf16x3_kernel(
    const ushort* __restrict__ Ahi, const ushort* __restrict__ Alo,
    const ushort* __restrict__ Bhi, const ushort* __restrict__ Blo,
    const float* __restrict__ bias, float* __restrict__ C,
    int M, int N, int K)
{
    __shared__ __align__(16) ushort lds[4 * 128 * 32];

    const int tid = threadIdx.x;
    const int wid = tid >> 6;
    const int lane = tid & 63;
    const int col0 = blockIdx.x * BN;
    const int row0 = blockIdx.y * BM;
    const int wy = wid >> 1, wx = wid & 1;

    const ushort* src = (wid == 0) ? Ahi : (wid == 1) ? Alo : (wid == 2) ? Bhi : Blo;
    const int srow = (wid < 2) ? row0 : col0;
    ushort* lbase = lds + wid * 4096;
    const int lrow = lane >> 2;
    const int lchunk = lane & 3;

    f32x4 acc[4][4] = {};

    for (int k0 = 0; k0 < K; k0 += BK) {
        __syncthreads();
        {
            const ushort* g0 = src + (size_t)(srow + lrow) * K + k0 + lchunk * 8;
            ushort* l0 = lbase + lane * 8;
            #pragma unroll
            for (int t = 0; t < 8; ++t) {
                __builtin_amdgcn_global_load_lds(
                    (const __attribute__((address_space(1))) unsigned int*)(g0 + (size_t)t * 16 * K),
                    (__attribute__((address_space(3))) unsigned int*)(l0 + t * 512),
                    16, 0, 0);
            }
        }
        __syncthreads();

        const int q = lane >> 4;
        const int r = lane & 15;
        bf16x8 ah[4], al[4], bh[4], bl[4];
        #pragma unroll
        for (int i = 0; i < 4; ++i) {
            int arow = wy * 64 + i * 16 + r;
            ah[i] = *(const bf16x8*)(lds + 0 * 4096 + arow * 32 + q * 8);
            al[i] = *(const bf16x8*)(lds + 1 * 4096 + arow * 32 + q * 8);
            int brow = wx * 64 + i * 16 + r;
            bh[i] = *(const bf16x8*)(lds + 2 * 4096 + brow * 32 + q * 8);
            bl[i] = *(const bf16x8*)(lds + 3 * 4096 + brow * 32 + q * 8);
        }
        #pragma unroll
        for (int i = 0; i < 4; ++i) {
            #pragma unroll
            for (int j = 0; j < 4; ++j) {
                acc[i][j] = __builtin_amdgcn_mfma_f32_16x16x32_bf16(al[i], bh[j], acc[i][j], 0, 0, 0);
                acc[i][j] = __builtin_amdgcn_mfma_f32_16x16x32_bf16(ah[i], bl[j], acc[i][j], 0, 0, 0);
                acc[i][j] = __builtin_amdgcn_mfma_f32_16x16x32_bf16(ah[i], bh[j], acc[i][j], 0, 0, 0);
            }
        }
    }

    const int q = lane >> 4, r = lane & 15;
    #pragma unroll
    for (int i = 0; i < 4; ++i) {
        #pragma unroll
        for (int j = 0; j < 4; ++j) {
            int col = col0 + wx * 64 + j * 16 + r;
            float b = bias[col];
            #pragma unroll
            for (int v = 0; v < 4; ++v) {
                int row = row0 + wy * 64 + i * 16 + q * 4 + v;
                C[(size_t)row * N + col] = acc[i][j][v] + b;
            }
        }
    }
}

// ---------------------------------------------------------------------------
// RoPE + scale + hi/lo split + head-major relayout.
// Reads qkv fp32 (b,n,3,H,80). Writes:
//   q_hi/q_lo [bh][n][96]  (RoPE'd, * SM_SCALE, d 80..95 zero-padded)
//   k_hi/k_lo [bh][n][80]  (RoPE'd)
//   vt_hi/vt_lo [bh][80][2048]  (V transposed)
// Grid (NN/64, HEADS, BB), 256 threads; each block: one (b,h,64-token) tile.
// ---------------------------------------------------------------------------
__global__ __launch_bounds__(256) void rope_split_kernel(
    const float* __restrict__ qkv, const float* __restrict__ cos_t,
    const float* __restrict__ sin_t,
    ushort* __restrict__ q_hi, ushort* __restrict__ q_lo,
    ushort* __restrict__ k_hi, ushort* __restrict__ k_lo,
    ushort* __restrict__ vt_hi, ushort* __restrict__ vt_lo)
{
    __shared__ float s_v[64][84];
    const int tid = threadIdx.x;
    const int b = blockIdx.z, h = blockIdx.y;
    const int n0 = blockIdx.x * 64;
    const int bh = b * HEADS + h;

    // V tile -> LDS (coalesced float4 loads)
    #pragma unroll
    for (int i = 0; i < 5; ++i) {
        int u = tid + i * 256;
        int n = u / 20, c = u % 20;
        const float* src = qkv + (size_t)(b * NN + n0 + n) * 3840 + 2 * HIDDEN + h * HD + c * 4;
        *(float4*)(&s_v[n][c * 4]) = *(const float4*)src;
    }

    // q,k RoPE + split (each unit: one (n, d-pair-of-2))
    #pragma unroll
    for (int i = 0; i < 5; ++i) {
        int u = tid + i * 256;
        int n = u / 20, p = u % 20;
        int d = p * 2;
        int ng = n0 + n;
        size_t row = (size_t)(b * NN + ng) * 3840;
        float2 c0 = *(const float2*)(cos_t + ng * HD + d);
        float2 c1 = *(const float2*)(cos_t + ng * HD + d + HALF);
        float2 s0 = *(const float2*)(sin_t + ng * HD + d);
        float2 s1 = *(const float2*)(sin_t + ng * HD + d + HALF);
        // q (scaled)
        {
            float2 x0 = *(const float2*)(qkv + row + h * HD + d);
            float2 x1 = *(const float2*)(qkv + row + h * HD + d + HALF);
            float o0x = (x0.x * c0.x - x1.x * s0.x) * SM_SCALE;
            float o0y = (x0.y * c0.y - x1.y * s0.y) * SM_SCALE;
            float o1x = (x1.x * c1.x + x0.x * s1.x) * SM_SCALE;
            float o1y = (x1.y * c1.y + x0.y * s1.y) * SM_SCALE;
            size_t o = ((size_t)bh * NN + ng) * 96;
            ushort hx, lx, hy, ly;
            ushort2 th, tl;
            split2(o0x, hx, lx); split2(o0y, hy, ly);
            th.x = hx; th.y = hy; tl.x = lx; tl.y = ly;
            *(ushort2*)(q_hi + o + d) = th;
            *(ushort2*)(q_lo + o + d) = tl;
            split2(o1x, hx, lx); split2(o1y, hy, ly);
            th.x = hx; th.y = hy; tl.x = lx; tl.y = ly;
            *(ushort2*)(q_hi + o + d + HALF) = th;
            *(ushort2*)(q_lo + o + d + HALF) = tl;
        }
        // k (unscaled)
        {
            float2 x0 = *(const float2*)(qkv + row + HIDDEN + h * HD + d);
            float2 x1 = *(const float2*)(qkv + row + HIDDEN + h * HD + d + HALF);
            float o0x = x0.x * c0.x - x1.x * s0.x;
            float o0y = x0.y * c0.y - x1.y * s0.y;
            float o1x = x1.x * c1.x + x0.x * s1.x;
            float o1y = x1.y * c1.y + x0.y * s1.y;
            size_t o = ((size_t)bh * NN + ng) * 80;
            ushort hx, lx, hy, ly;
            ushort2 th, tl;
            split2(o0x, hx, lx); split2(o0y, hy, ly);
            th.x = hx; th.y = hy; tl.x = lx; tl.y = ly;
            *(ushort2*)(k_hi + o + d) = th;
            *(ushort2*)(k_lo + o + d) = tl;
            split2(o1x, hx, lx); split2(o1y, hy, ly);
            th.x = hx; th.y = hy; tl.x = lx; tl.y = ly;
            *(ushort2*)(k_hi + o + d + HALF) = th;
            *(ushort2*)(k_lo + o + d + HALF) = tl;
        }
    }

    // q pad zeros (d 80..95)
    {
        int n = tid >> 2, pp = tid & 3;
        size_t o = ((size_t)bh * NN + n0 + n) * 96 + 80 + pp * 4;
        ushort4 z;
        z.x = 0; z.y = 0; z.z = 0; z.w = 0;
        *(ushort4*)(q_hi + o) = z;
        *(ushort4*)(q_lo + o) = z;
    }
    __syncthreads();

    // V^T write: unit = (d, 16-token chunk)
    for (int u = tid; u < 320; u += 256) {
        int d = u >> 2, nc = u & 3;
        ushort hs[16], ls[16];
        #pragma unroll
        for (int kk = 0; kk < 16; ++kk)
            split2(s_v[nc * 16 + kk][d], hs[kk], ls[kk]);
        size_t o = ((size_t)bh * HD + d) * NN + n0 + nc * 16;
        uint4 w0, w1;
        w0.x = (uint)hs[0] | ((uint)hs[1] << 16);
        w0.y = (uint)hs[2] | ((uint)hs[3] << 16);
        w0.z = (uint)hs[4] | ((uint)hs[5] << 16);
        w0.w = (uint)hs[6] | ((uint)hs[7] << 16);
        w1.x = (uint)hs[8] | ((uint)hs[9] << 16);
        w1.y = (uint)hs[10] | ((uint)hs[11] << 16);
        w1.z = (uint)hs[12] | ((uint)hs[13] << 16);
        w1.w = (uint)hs[14] | ((uint)hs[15] << 16);
        *(uint4*)(vt_hi + o) = w0;
        *(uint4*)(vt_hi + o + 8) = w1;
        w0.x = (uint)ls[0] | ((uint)ls[1] << 16);
        w0.y = (uint)ls[2] | ((uint)ls[3] << 16);
        w0.z = (uint)ls[4] | ((uint)ls[5] << 16);
        w0.w = (uint)ls[6] | ((uint)ls[7] << 16);
        w1.x = (uint)ls[8] | ((uint)ls[9] << 16);
        w1.y = (uint)ls[10] | ((uint)ls[11] << 16);
        w1.z = (uint)ls[12] | ((uint)ls[13] << 16);
        w1.w = (uint)ls[14] | ((uint)ls[15] << 16);
        *(uint4*)(vt_lo + o) = w0;
        *(uint4*)(vt_lo + o + 8) = w1;
    }
}

// ---------------------------------------------------------------------------
// MFMA flash attention, bf16x3 precision.
// Block = 256 threads = 4 waves; each wave owns 32 q-rows (2 m-tiles).
// Key tiles of 64, staged hi/lo via global_load_lds. Online softmax in
// C-layout registers; P -> LDS (wave-private) -> A-layout frags; PV with
// V^T b-frags. Output written split hi/lo to ao (row-major [4096][1280]).
// ---------------------------------------------------------------------------
__global__ __launch_bounds__(256, 2) void attn_mfma_kernel(
    const ushort* __restrict__ q_hi, const ushort* __restrict__ q_lo,
    const ushort* __restrict__ k_hi, const ushort* __restrict__ k_lo,
    const ushort* __restrict__ vt_hi, const ushort* __restrict__ vt_lo,
    ushort* __restrict__ ao_hi, ushort* __restrict__ ao_lo)
{
    __shared__ __align__(16) ushort lds[36864];   // 73728 B
    ushort* kh_s = lds;              // [64][80]
    ushort* kl_s = lds + 5120;
    ushort* vh_s = lds + 10240;      // [80][64]
    ushort* vl_s = lds + 15360;
    ushort* ph_s = lds + 20480;      // [128][64]
    ushort* pl_s = lds + 28672;

    const int tid = threadIdx.x;
    const int wave = tid >> 6, lane = tid & 63;
    const int quad = lane >> 4, r = lane & 15;
    const int b = blockIdx.z, h = blockIdx.y;
    const int bh = b * HEADS + h;
    const int q0 = blockIdx.x * 128;

    // Q a-frags direct from global (row*96 layout, zero pad covers c=2 tail)
    bf16x8 qfh[2][3], qfl[2][3];
    #pragma unroll
    for (int mt = 0; mt < 2; ++mt)
        #pragma unroll
        for (int c = 0; c < 3; ++c) {
            size_t o = ((size_t)bh * NN + q0 + wave * 32 + mt * 16 + r) * 96 + c * 32 + quad * 8;
            qfh[mt][c] = *(const bf16x8*)(q_hi + o);
            qfl[mt][c] = *(const bf16x8*)(q_lo + o);
        }

    f32x4 oacc[2][5] = {};
    float m_r[2][4], l_r[2][4];
    #pragma unroll
    for (int mt = 0; mt < 2; ++mt)
        #pragma unroll
        for (int v = 0; v < 4; ++v) { m_r[mt][v] = -INFINITY; l_r[mt][v] = 0.0f; }

    const size_t kb = (size_t)bh * NN * HD;
    const size_t vb = (size_t)bh * HD * NN;

    for (int j0 = 0; j0 < NN; j0 += 64) {
        __syncthreads();
        // stage K (linear) and V^T (8 rows / KB) tiles, hi+lo
        for (int i = wave; i < 10; i += 4) {
            int off = i * 512 + lane * 8;  // ushort units; *2 = bytes
            __builtin_amdgcn_global_load_lds(
                (const __attribute__((address_space(1))) unsigned int*)(k_hi + kb + (size_t)j0 * HD + off),
                (__attribute__((address_space(3))) unsigned int*)(kh_s + off), 16, 0, 0);
            __builtin_amdgcn_global_load_lds(
                (const __attribute__((address_space(1))) unsigned int*)(k_lo + kb + (size_t)j0 * HD + off),
                (__attribute__((address_space(3))) unsigned int*)(kl_s + off), 16, 0, 0);
            int drow = i * 8 + (lane >> 3);
            size_t go = vb + (size_t)drow * NN + j0 + (lane & 7) * 8;
            __builtin_amdgcn_global_load_lds(
                (const __attribute__((address_space(1))) unsigned int*)(vt_hi + go),
                (__attribute__((address_space(3))) unsigned int*)(vh_s + off), 16, 0, 0);
            __builtin_amdgcn_global_load_lds(
                (const __attribute__((address_space(1))) unsigned int*)(vt_lo + go),
                (__attribute__((address_space(3))) unsigned int*)(vl_s + off), 16, 0, 0);
        }
        __syncthreads();

        // QK^T: scores in C-layout (col=j=lane&15 within tile, row=quad*4+v)
        f32x4 sc[2][4] = {};
        #pragma unroll
        for (int jt = 0; jt < 4; ++jt) {
            bf16x8 kbh[3], kbl[3];
            int j = jt * 16 + r;
            #pragma unroll
            for (int c = 0; c < 3; ++c) {
                int a = j * HD + c * 32 + quad * 8;
                kbh[c] = *(const bf16x8*)(kh_s + a);
                kbl[c] = *(const bf16x8*)(kl_s + a);
            }
            #pragma unroll
            for (int mt = 0; mt < 2; ++mt)
                #pragma unroll
                for (int c = 0; c < 3; ++c) {
                    sc[mt][jt] = __builtin_amdgcn_mfma_f32_16x16x32_bf16(qfl[mt][c], kbh[c], sc[mt][jt], 0, 0, 0);
                    sc[mt][jt] = __builtin_amdgcn_mfma_f32_16x16x32_bf16(qfh[mt][c], kbl[c], sc[mt][jt], 0, 0, 0);
                    sc[mt][jt] = __builtin_amdgcn_mfma_f32_16x16x32_bf16(qfh[mt][c], kbh[c], sc[mt][jt], 0, 0, 0);
                }
        }

        // online softmax + P split to LDS
        #pragma unroll
        for (int mt = 0; mt < 2; ++mt) {
            float al[4];
            #pragma unroll
            for (int v = 0; v < 4; ++v) {
                float tm = fmaxf(fmaxf(sc[mt][0][v], sc[mt][1][v]),
                                 fmaxf(sc[mt][2][v], sc[mt][3][v]));
                tm = fmaxf(tm, __shfl_xor(tm, 1));
                tm = fmaxf(tm, __shfl_xor(tm, 2));
                tm = fmaxf(tm, __shfl_xor(tm, 4));
                tm = fmaxf(tm, __shfl_xor(tm, 8));
                float mn = fmaxf(m_r[mt][v], tm);
                al[v] = __expf(m_r[mt][v] - mn);
                m_r[mt][v] = mn;
                float ps = 0.0f;
                #pragma unroll
                for (int jt = 0; jt < 4; ++jt) {
                    float p = __expf(sc[mt][jt][v] - mn);
                    sc[mt][jt][v] = p;
                    ps += p;
                }
                ps += __shfl_xor(ps, 1);
                ps += __shfl_xor(ps, 2);
                ps += __shfl_xor(ps, 4);
                ps += __shfl_xor(ps, 8);
                l_r[mt][v] = l_r[mt][v] * al[v] + ps;
            }
            int qrow = wave * 32 + mt * 16 + quad * 4;
            #pragma unroll
            for (int jt = 0; jt < 4; ++jt)
                #pragma unroll
                for (int v = 0; v < 4; ++v) {
                    ushort hh, ll;
                    split2(sc[mt][jt][v], hh, ll);
                    int a = (qrow + v) * 64 + jt * 16 + r;
                    ph_s[a] = hh;
                    pl_s[a] = ll;
                }
            #pragma unroll
            for (int dt = 0; dt < 5; ++dt)
                #pragma unroll
                for (int v = 0; v < 4; ++v)
                    oacc[mt][dt][v] *= al[v];
        }

        // PV: P a-frags (wave-private LDS rows), V^T b-frags
        bf16x8 pah[2][2], pal[2][2];
        #pragma unroll
        for (int mt = 0; mt < 2; ++mt)
            #pragma unroll
            for (int cc = 0; cc < 2; ++cc) {
                int a = (wave * 32 + mt * 16 + r) * 64 + cc * 32 + quad * 8;
                pah[mt][cc] = *(const bf16x8*)(ph_s + a);
                pal[mt][cc] = *(const bf16x8*)(pl_s + a);
            }
        #pragma unroll
        for (int dt = 0; dt < 5; ++dt)
            #pragma unroll
            for (int cc = 0; cc < 2; ++cc) {
                int a = (dt * 16 + r) * 64 + cc * 32 + quad * 8;
                bf16x8 vbh = *(const bf16x8*)(vh_s + a);
                bf16x8 vbl = *(const bf16x8*)(vl_s + a);
                #pragma unroll
                for (int mt = 0; mt < 2; ++mt) {
                    oacc[mt][dt] = __builtin_amdgcn_mfma_f32_16x16x32_bf16(pal[mt][cc], vbh, oacc[mt][dt], 0, 0, 0);
                    oacc[mt][dt] = __builtin_amdgcn_mfma_f32_16x16x32_bf16(pah[mt][cc], vbl, oacc[mt][dt], 0, 0, 0);
                    oacc[mt][dt] = __builtin_amdgcn_mfma_f32_16x16x32_bf16(pah[mt][cc], vbh, oacc[mt][dt], 0, 0, 0);
                }
            }
    }

    // epilogue: normalize, split, store
    #pragma unroll
    for (int mt = 0; mt < 2; ++mt)
        #pragma unroll
        for (int v = 0; v < 4; ++v) {
            float inv = 1.0f / l_r[mt][v];
            size_t row = (size_t)b * NN + q0 + wave * 32 + mt * 16 + quad * 4 + v;
            #pragma unroll
            for (int dt = 0; dt < 5; ++dt) {
                float o = oacc[mt][dt][v] * inv;
                ushort hh, ll;
                split2(o, hh, ll);
                size_t idx = row * HIDDEN + h * HD + dt * 16 + r;
                ao_hi[idx] = hh;
                ao_lo[idx] = ll;
            }
        }
}

// ---------------------------------------------------------------------------
extern "C" void kernel_launch(void* const* d_in, const int* in_sizes, int n_in,
                              void* d_out, int out_size, void* d_ws, size_t ws_size,
                              hipStream_t stream)
{
    const float* x      = (const float*)d_in[0];
    const float* cos_t  = (const float*)d_in[1];
    const float* sin_t  = (const float*)d_in[2];
    const float* qkv_w  = (const float*)d_in[3];
    const float* qkv_b  = (const float*)d_in[4];
    const float* proj_w = (const float*)d_in[5];
    const float* proj_b = (const float*)d_in[6];
    float* out = (float*)d_out;

    char* ws = (char*)d_ws;
    // layout (bytes):
    //   [0, 62914560)           qkv fp32 (dead after rope_split)
    //     -> reused: ao_hi at 0 (10485760), ao_lo at 10485760
    //   [62914560, +9830400)    wT_hi   (qkv_w T; reused for proj)
    //   [72744960, +9830400)    wT_lo
    //   [82575360, +10485760)   a_hi (x split) -> reused as k_hi
    //   [93061120, +10485760)   a_lo (x split) -> reused as k_lo
    //   [103546880, +12582912)  q_hi  [32][2048][96]
    //   [116129792, +12582912)  q_lo
    //   [128712704, +10485760)  vt_hi [32][80][2048]
    //   [139198464, +10485760)  vt_lo    (end 149684224)
    float*  qkv   = (float*)ws;
    ushort* ao_hi = (ushort*)ws;
    ushort* ao_lo = (ushort*)(ws + 10485760);
    ushort* wT_hi = (ushort*)(ws + 62914560);
    ushort* wT_lo = (ushort*)(ws + 72744960);
    ushort* a_hi  = (ushort*)(ws + 82575360);
    ushort* a_lo  = (ushort*)(ws + 93061120);
    ushort* q_hi  = (ushort*)(ws + 103546880);
    ushort* q_lo  = (ushort*)(ws + 116129792);
    ushort* vt_hi = (ushort*)(ws + 128712704);
    ushort* vt_lo = (ushort*)(ws + 139198464);

    // 1) split x into bf16 hi/lo
    split_kernel<<<(MROWS * HIDDEN / 4 + 255) / 256, 256, 0, stream>>>(
        x, a_hi, a_lo, MROWS * HIDDEN / 4);

    // 2) transpose+split qkv_w
    tsplit_kernel<<<dim3(3 * HIDDEN / 32, HIDDEN / 32), 256, 0, stream>>>(
        qkv_w, wT_hi, wT_lo, HIDDEN, 3 * HIDDEN);

    // 3) qkv = x @ qkv_w + qkv_b
    gemm_bf16x3_kernel<<<dim3(3 * HIDDEN / BN, MROWS / BM), 256, 0, stream>>>(
        a_hi, a_lo, wT_hi, wT_lo, qkv_b, qkv, MROWS, 3 * HIDDEN, HIDDEN);

    // 4) RoPE + split + relayout (k overwrites a_hi/a_lo — x split is dead)
    rope_split_kernel<<<dim3(NN / 64, HEADS, BB), 256, 0, stream>>>(
        qkv, cos_t, sin_t, q_hi, q_lo, a_hi, a_lo, vt_hi, vt_lo);

    // 5) MFMA flash attention (ao overwrites qkv region — dead now)
    attn_mfma_kernel<<<dim3(NN / 128, HEADS, BB), 256, 0, stream>>>(
        q_hi, q_lo, a_hi, a_lo, vt_hi, vt_lo, ao_hi, ao_lo);

    // 6) transpose+split proj_w
    tsplit_kernel<<<dim3(HIDDEN / 32, HIDDEN / 32), 256, 0, stream>>>(
        proj_w, wT_hi, wT_lo, HIDDEN, HIDDEN);

    // 7) out = attn_out @ proj_w + proj_b
    gemm_bf16x3_kernel<<<dim3(HIDDEN / BN, MROWS / BM), 256, 0, stream>>>(
        ao_hi, ao_lo, wT_hi, wT_lo, proj_b, out, MROWS, HIDDEN, HIDDEN);
}

// Round 5
// 493.547 us; speedup vs baseline: 3.5257x; 1.0683x over previous
//
#include <hip/hip_runtime.h>
#include <hip/hip_bf16.h>
#include <math.h>

#define HIDDEN 1280
#define HEADS 16
#define HD 80           // head dim
#define HALF 40
#define BB 2
#define NN 2048
#define MROWS (BB * NN) // 4096
// 1/sqrt(80) * log2(e): scores come out in log2 domain -> exp2 directly
#define QSCALE ((float)(0.11180339887498949 * 1.4426950408889634))

typedef __attribute__((ext_vector_type(8))) __bf16 bf16x8;
typedef __attribute__((ext_vector_type(4))) float f32x4;

// Split fp32 into bf16 hi + bf16 lo (hi+lo carries ~16 mantissa bits).
__device__ __forceinline__ void split2(float x, ushort& hi, ushort& lo) {
    __hip_bfloat16 h = __float2bfloat16(x);
    float r = x - __bfloat162float(h);
    __hip_bfloat16 l = __float2bfloat16(r);
    hi = __builtin_bit_cast(ushort, h);
    lo = __builtin_bit_cast(ushort, l);
}

__device__ __forceinline__ ushort4 split4hi(float4 v, ushort4& lo4) {
    ushort4 h;
    split2(v.x, h.x, lo4.x);
    split2(v.y, h.y, lo4.y);
    split2(v.z, h.z, lo4.z);
    split2(v.w, h.w, lo4.w);
    return h;
}

// ---------------------------------------------------------------------------
// Elementwise split: fp32 [n] -> bf16 hi[n], lo[n]. 4 elems/thread.
// ---------------------------------------------------------------------------
__global__ __launch_bounds__(256) void split_kernel(
    const float* __restrict__ in, ushort* __restrict__ hi,
    ushort* __restrict__ lo, int n4)
{
    int i = blockIdx.x * 256 + threadIdx.x;
    if (i >= n4) return;
    float4 v = ((const float4*)in)[i];
    ushort4 h, l;
    h = split4hi(v, l);
    ((ushort4*)hi)[i] = h;
    ((ushort4*)lo)[i] = l;
}

// ---------------------------------------------------------------------------
// Transpose + split: W[K][N] fp32 -> WT_hi[N][K], WT_lo[N][K] bf16.
// ---------------------------------------------------------------------------
__global__ __launch_bounds__(256) void tsplit_kernel(
    const float* __restrict__ W, ushort* __restrict__ Thi,
    ushort* __restrict__ Tlo, int K, int N)
{
    __shared__ float s[32][33];
    const int n0 = blockIdx.x * 32;
    const int k0 = blockIdx.y * 32;
    {
        int tn = threadIdx.x & 31, tk = threadIdx.x >> 5;
        #pragma unroll
        for (int i = 0; i < 4; ++i)
            s[tk + i * 8][tn] = W[(size_t)(k0 + tk + i * 8) * N + n0 + tn];
    }
    __syncthreads();
    {
        int tk = threadIdx.x & 31, tn = threadIdx.x >> 5;
        #pragma unroll
        for (int i = 0; i < 4; ++i) {
            float v = s[tk][tn + i * 8];
            ushort h, l;
            split2(v, h, l);
            size_t o = (size_t)(n0 + tn + i * 8) * K + k0 + tk;
            Thi[o] = h;
            Tlo[o] = l;
        }
    }
}

// ---------------------------------------------------------------------------
// bf16x3 MFMA GEMM: C[M,N] = (Ahi+Alo)[M,K] @ (Bhi+Blo)[N,K]^T + bias[N]
// ---------------------------------------------------------------------------
#define BM 128
#define BN 128
#define BK 32

__global__ __launch_bounds__(256) void gemm_bf16x3_kernel(
    const ushort* __restrict__ Ahi, const ushort* __restrict__ Alo,
    const ushort* __restrict__ Bhi, const ushort* __restrict__ Blo,
    const float* __restrict__ bias, float* __restrict__ C,
    int M, int N, int K)
{
    __shared__ __align__(16) ushort lds[4 * 128 * 32];

    const int tid = threadIdx.x;
    const int wid = tid >> 6;
    const int lane = tid & 63;
    const int col0 = blockIdx.x * BN;
    const int row0 = blockIdx.y * BM;
    const int wy = wid >> 1, wx = wid & 1;

    const ushort* src = (wid == 0) ? Ahi : (wid == 1) ? Alo : (wid == 2) ? Bhi : Blo;
    const int srow = (wid < 2) ? row0 : col0;
    ushort* lbase = lds + wid * 4096;
    const int lrow = lane >> 2;
    const int lchunk = lane & 3;

    f32x4 acc[4][4] = {};

    for (int k0 = 0; k0 < K; k0 += BK) {
        __syncthreads();
        {
            const ushort* g0 = src + (size_t)(srow + lrow) * K + k0 + lchunk * 8;
            ushort* l0 = lbase + lane * 8;
            #pragma unroll
            for (int t = 0; t < 8; ++t) {
                __builtin_amdgcn_global_load_lds(
                    (const __attribute__((address_space(1))) unsigned int*)(g0 + (size_t)t * 16 * K),
                    (__attribute__((address_space(3))) unsigned int*)(l0 + t * 512),
                    16, 0, 0);
            }
        }
        __syncthreads();

        const int q = lane >> 4;
        const int r = lane & 15;
        bf16x8 ah[4], al[4], bh[4], bl[4];
        #pragma unroll
        for (int i = 0; i < 4; ++i) {
            int arow = wy * 64 + i * 16 + r;
            ah[i] = *(const bf16x8*)(lds + 0 * 4096 + arow * 32 + q * 8);
            al[i] = *(const bf16x8*)(lds + 1 * 4096 + arow * 32 + q * 8);
            int brow = wx * 64 + i * 16 + r;
            bh[i] = *(const bf16x8*)(lds + 2 * 4096 + brow * 32 + q * 8);
            bl[i] = *(const bf16x8*)(lds + 3 * 4096 + brow * 32 + q * 8);
        }
        #pragma unroll
        for (int i = 0; i < 4; ++i) {
            #pragma unroll
            for (int j = 0; j < 4; ++j) {
                acc[i][j] = __builtin_amdgcn_mfma_f32_16x16x32_bf16(al[i], bh[j], acc[i][j], 0, 0, 0);
                acc[i][j] = __builtin_amdgcn_mfma_f32_16x16x32_bf16(ah[i], bl[j], acc[i][j], 0, 0, 0);
                acc[i][j] = __builtin_amdgcn_mfma_f32_16x16x32_bf16(ah[i], bh[j], acc[i][j], 0, 0, 0);
            }
        }
    }

    const int q = lane >> 4, r = lane & 15;
    #pragma unroll
    for (int i = 0; i < 4; ++i) {
        #pragma unroll
        for (int j = 0; j < 4; ++j) {
            int col = col0 + wx * 64 + j * 16 + r;
            float b = bias[col];
            #pragma unroll
            for (int v = 0; v < 4; ++v) {
                int row = row0 + wy * 64 + i * 16 + q * 4 + v;
                C[(size_t)row * N + col] = acc[i][j][v] + b;
            }
        }
    }
}

// ---------------------------------------------------------------------------
// RoPE + scale + hi/lo split + head-major relayout.
// Reads qkv fp32 (b,n,3,H,80). Writes:
//   q_hi/q_lo [bh][n][96]  (RoPE'd, * QSCALE, d 80..95 zeroed)
//   k_hi/k_lo [bh][n][96]  (RoPE'd, d 80..95 zeroed)
//   vt_hi/vt_lo [bh][80][2048]  (V transposed)
// Grid (NN/64, HEADS, BB), 256 threads.
// ---------------------------------------------------------------------------
__global__ __launch_bounds__(256) void rope_split_kernel(
    const float* __restrict__ qkv, const float* __restrict__ cos_t,
    const float* __restrict__ sin_t,
    ushort* __restrict__ q_hi, ushort* __restrict__ q_lo,
    ushort* __restrict__ k_hi, ushort* __restrict__ k_lo,
    ushort* __restrict__ vt_hi, ushort* __restrict__ vt_lo)
{
    __shared__ float s_v[64][84];
    const int tid = threadIdx.x;
    const int b = blockIdx.z, h = blockIdx.y;
    const int n0 = blockIdx.x * 64;
    const int bh = b * HEADS + h;

    // V tile -> LDS (coalesced float4 loads)
    #pragma unroll
    for (int i = 0; i < 5; ++i) {
        int u = tid + i * 256;
        int n = u / 20, c = u % 20;
        const float* src = qkv + (size_t)(b * NN + n0 + n) * 3840 + 2 * HIDDEN + h * HD + c * 4;
        *(float4*)(&s_v[n][c * 4]) = *(const float4*)src;
    }

    // q,k RoPE + split: 640 units, each = (token n, 4-wide d group in [0,40))
    for (int u = tid; u < 640; u += 256) {
        int n = u / 10, p = u % 10;
        int d = p * 4;
        int ng = n0 + n;
        size_t rowb = (size_t)(b * NN + ng) * 3840;
        float4 c0 = *(const float4*)(cos_t + ng * HD + d);
        float4 c1 = *(const float4*)(cos_t + ng * HD + d + HALF);
        float4 s0 = *(const float4*)(sin_t + ng * HD + d);
        float4 s1 = *(const float4*)(sin_t + ng * HD + d + HALF);
        size_t qo = ((size_t)bh * NN + ng) * 96;
        // q (scaled by QSCALE so scores are in log2 domain)
        {
            float4 x0 = *(const float4*)(qkv + rowb + h * HD + d);
            float4 x1 = *(const float4*)(qkv + rowb + h * HD + d + HALF);
            float4 o0, o1;
            o0.x = (x0.x * c0.x - x1.x * s0.x) * QSCALE;
            o0.y = (x0.y * c0.y - x1.y * s0.y) * QSCALE;
            o0.z = (x0.z * c0.z - x1.z * s0.z) * QSCALE;
            o0.w = (x0.w * c0.w - x1.w * s0.w) * QSCALE;
            o1.x = (x1.x * c1.x + x0.x * s1.x) * QSCALE;
            o1.y = (x1.y * c1.y + x0.y * s1.y) * QSCALE;
            o1.z = (x1.z * c1.z + x0.z * s1.z) * QSCALE;
            o1.w = (x1.w * c1.w + x0.w * s1.w) * QSCALE;
            ushort4 h4, l4;
            h4 = split4hi(o0, l4);
            *(ushort4*)(q_hi + qo + d) = h4;
            *(ushort4*)(q_lo + qo + d) = l4;
            h4 = split4hi(o1, l4);
            *(ushort4*)(q_hi + qo + d + HALF) = h4;
            *(ushort4*)(q_lo + qo + d + HALF) = l4;
        }
        // k (unscaled)
        {
            float4 x0 = *(const float4*)(qkv + rowb + HIDDEN + h * HD + d);
            float4 x1 = *(const float4*)(qkv + rowb + HIDDEN + h * HD + d + HALF);
            float4 o0, o1;
            o0.x = x0.x * c0.x - x1.x * s0.x;
            o0.y = x0.y * c0.y - x1.y * s0.y;
            o0.z = x0.z * c0.z - x1.z * s0.z;
            o0.w = x0.w * c0.w - x1.w * s0.w;
            o1.x = x1.x * c1.x + x0.x * s1.x;
            o1.y = x1.y * c1.y + x0.y * s1.y;
            o1.z = x1.z * c1.z + x0.z * s1.z;
            o1.w = x1.w * c1.w + x0.w * s1.w;
            ushort4 h4, l4;
            h4 = split4hi(o0, l4);
            *(ushort4*)(k_hi + qo + d) = h4;
            *(ushort4*)(k_lo + qo + d) = l4;
            h4 = split4hi(o1, l4);
            *(ushort4*)(k_hi + qo + d + HALF) = h4;
            *(ushort4*)(k_lo + qo + d + HALF) = l4;
        }
    }

    // zero the d=80..95 pad for q and k (both planes). 256 units exactly.
    {
        int n = tid >> 2;
        int which = (tid >> 1) & 1;
        int cpart = tid & 1;
        size_t o = ((size_t)bh * NN + n0 + n) * 96 + 80 + cpart * 8;
        uint4 z = {0u, 0u, 0u, 0u};
        if (which == 0) {
            *(uint4*)(q_hi + o) = z;
            *(uint4*)(q_lo + o) = z;
        } else {
            *(uint4*)(k_hi + o) = z;
            *(uint4*)(k_lo + o) = z;
        }
    }
    __syncthreads();

    // V^T write: unit = (d, 16-token chunk)
    for (int u = tid; u < 320; u += 256) {
        int d = u >> 2, nc = u & 3;
        ushort hs[16], ls[16];
        #pragma unroll
        for (int kk = 0; kk < 16; ++kk)
            split2(s_v[nc * 16 + kk][d], hs[kk], ls[kk]);
        size_t o = ((size_t)bh * HD + d) * NN + n0 + nc * 16;
        uint4 w0, w1;
        w0.x = (uint)hs[0] | ((uint)hs[1] << 16);
        w0.y = (uint)hs[2] | ((uint)hs[3] << 16);
        w0.z = (uint)hs[4] | ((uint)hs[5] << 16);
        w0.w = (uint)hs[6] | ((uint)hs[7] << 16);
        w1.x = (uint)hs[8] | ((uint)hs[9] << 16);
        w1.y = (uint)hs[10] | ((uint)hs[11] << 16);
        w1.z = (uint)hs[12] | ((uint)hs[13] << 16);
        w1.w = (uint)hs[14] | ((uint)hs[15] << 16);
        *(uint4*)(vt_hi + o) = w0;
        *(uint4*)(vt_hi + o + 8) = w1;
        w0.x = (uint)ls[0] | ((uint)ls[1] << 16);
        w0.y = (uint)ls[2] | ((uint)ls[3] << 16);
        w0.z = (uint)ls[4] | ((uint)ls[5] << 16);
        w0.w = (uint)ls[6] | ((uint)ls[7] << 16);
        w1.x = (uint)ls[8] | ((uint)ls[9] << 16);
        w1.y = (uint)ls[10] | ((uint)ls[11] << 16);
        w1.z = (uint)ls[12] | ((uint)ls[13] << 16);
        w1.w = (uint)ls[14] | ((uint)ls[15] << 16);
        *(uint4*)(vt_lo + o) = w0;
        *(uint4*)(vt_lo + o + 8) = w1;
    }
}

// ---------------------------------------------------------------------------
// MFMA flash attention v2, bf16x3.
//  - no-max softmax (scores bounded; exp2 in log2 domain), deferred l-reduce
//  - K tiles 96-wide (pad zeroed) -> linear staging, conflict-free reads
//  - V^T staged with source-side XOR swizzle -> uniform reads
//  - P tiles with 16B-block XOR swizzle -> conflict-free writes/reads
//  - epilogue assembled in LDS, uint4 global stores
// ---------------------------------------------------------------------------
__global__ __launch_bounds__(256, 2) void attn_mfma_kernel(
    const ushort* __restrict__ q_hi, const ushort* __restrict__ q_lo,
    const ushort* __restrict__ k_hi, const ushort* __restrict__ k_lo,
    const ushort* __restrict__ vt_hi, const ushort* __restrict__ vt_lo,
    ushort* __restrict__ ao_hi, ushort* __restrict__ ao_lo)
{
    __shared__ __align__(16) ushort lds[38912];   // 77824 B
    ushort* kh_s = lds;              // [64][96] = 6144
    ushort* kl_s = lds + 6144;
    ushort* vh_s = lds + 12288;      // [80][64] chunk-swizzled = 5120
    ushort* vl_s = lds + 17408;
    ushort* ph_s = lds + 22528;      // [128][64] block-swizzled = 8192
    ushort* pl_s = lds + 30720;

    const int tid = threadIdx.x;
    const int wave = tid >> 6, lane = tid & 63;
    const int quad = lane >> 4, r = lane & 15;
    const int b = blockIdx.z, h = blockIdx.y;
    const int bh = b * HEADS + h;
    const int q0 = blockIdx.x * 128;

    // Q a-frags from [bh][n][96] (pre-scaled by QSCALE, pad zero)
    bf16x8 qfh[2][3], qfl[2][3];
    #pragma unroll
    for (int mt = 0; mt < 2; ++mt)
        #pragma unroll
        for (int c = 0; c < 3; ++c) {
            size_t o = ((size_t)bh * NN + q0 + wave * 32 + mt * 16 + r) * 96 + c * 32 + quad * 8;
            qfh[mt][c] = *(const bf16x8*)(q_hi + o);
            qfl[mt][c] = *(const bf16x8*)(q_lo + o);
        }

    f32x4 oacc[2][5] = {};
    float l_part[2][4] = {};

    const size_t kb = (size_t)bh * NN * 96;
    const size_t vb = (size_t)bh * HD * NN;

    for (int j0 = 0; j0 < NN; j0 += 64) {
        __syncthreads();
        // stage K (linear, 12 segs/plane) + V^T (src-swizzled, 10 segs/plane)
        for (int s = wave; s < 44; s += 4) {
            if (s < 24) {
                const ushort* gp = (s < 12 ? k_hi : k_lo);
                ushort* lp = (s < 12 ? kh_s : kl_s);
                int seg = (s < 12) ? s : s - 12;
                int off = seg * 512 + lane * 8;
                __builtin_amdgcn_global_load_lds(
                    (const __attribute__((address_space(1))) unsigned int*)(gp + kb + (size_t)j0 * 96 + off),
                    (__attribute__((address_space(3))) unsigned int*)(lp + off), 16, 0, 0);
            } else {
                int t = s - 24;
                const ushort* gp = (t < 10 ? vt_hi : vt_lo);
                ushort* lp = (t < 10 ? vh_s : vl_s);
                int seg = (t < 10) ? t : t - 10;
                int row = seg * 8 + (lane >> 3);
                size_t go = vb + (size_t)row * NN + j0 + (size_t)(((lane & 7) ^ (lane >> 3)) * 8);
                __builtin_amdgcn_global_load_lds(
                    (const __attribute__((address_space(1))) unsigned int*)(gp + go),
                    (__attribute__((address_space(3))) unsigned int*)(lp + seg * 512 + lane * 8), 16, 0, 0);
            }
        }
        __syncthreads();

        // QK^T -> scores in C-layout (log2 domain)
        f32x4 sc[2][4] = {};
        #pragma unroll
        for (int jt = 0; jt < 4; ++jt) {
            bf16x8 kbh[3], kbl[3];
            int j = jt * 16 + r;
            #pragma unroll
            for (int c = 0; c < 3; ++c) {
                int a = j * 96 + c * 32 + quad * 8;
                kbh[c] = *(const bf16x8*)(kh_s + a);
                kbl[c] = *(const bf16x8*)(kl_s + a);
            }
            #pragma unroll
            for (int mt = 0; mt < 2; ++mt)
                #pragma unroll
                for (int c = 0; c < 3; ++c) {
                    sc[mt][jt] = __builtin_amdgcn_mfma_f32_16x16x32_bf16(qfl[mt][c], kbh[c], sc[mt][jt], 0, 0, 0);
                    sc[mt][jt] = __builtin_amdgcn_mfma_f32_16x16x32_bf16(qfh[mt][c], kbl[c], sc[mt][jt], 0, 0, 0);
                    sc[mt][jt] = __builtin_amdgcn_mfma_f32_16x16x32_bf16(qfh[mt][c], kbh[c], sc[mt][jt], 0, 0, 0);
                }
        }

        // no-max softmax: p = exp2(s); accumulate per-lane l partials
        #pragma unroll
        for (int mt = 0; mt < 2; ++mt) {
            #pragma unroll
            for (int v = 0; v < 4; ++v) {
                float ps = 0.0f;
                #pragma unroll
                for (int jt = 0; jt < 4; ++jt) {
                    float p = __builtin_amdgcn_exp2f(sc[mt][jt][v]);
                    sc[mt][jt][v] = p;
                    ps += p;
                }
                l_part[mt][v] += ps;
            }
            // P split -> LDS, 16B-block swizzle: blk' = blk ^ (quad<<1)
            int rowbase = wave * 32 + mt * 16 + quad * 4;
            #pragma unroll
            for (int jt = 0; jt < 4; ++jt) {
                int bk = jt * 2 + (r >> 3);
                int bks = bk ^ (quad << 1);
                #pragma unroll
                for (int v = 0; v < 4; ++v) {
                    ushort hh, ll;
                    split2(sc[mt][jt][v], hh, ll);
                    int a = (rowbase + v) * 64 + bks * 8 + (r & 7);
                    ph_s[a] = hh;
                    pl_s[a] = ll;
                }
            }
        }

        // P a-frags (wave-private rows, swizzled reads)
        bf16x8 pah[2][2], pal[2][2];
        #pragma unroll
        for (int mt = 0; mt < 2; ++mt)
            #pragma unroll
            for (int cc = 0; cc < 2; ++cc) {
                int rowp = wave * 32 + mt * 16 + r;
                int bks = (cc * 4 + quad) ^ (((r >> 2) & 3) << 1);
                int a = rowp * 64 + bks * 8;
                pah[mt][cc] = *(const bf16x8*)(ph_s + a);
                pal[mt][cc] = *(const bf16x8*)(pl_s + a);
            }

        // PV with V^T b-frags (chunk-swizzled reads)
        #pragma unroll
        for (int dt = 0; dt < 5; ++dt)
            #pragma unroll
            for (int cc = 0; cc < 2; ++cc) {
                int rowv = dt * 16 + r;
                int ck = (cc * 4 + quad) ^ (r & 7);
                int a = rowv * 64 + ck * 8;
                bf16x8 vbh = *(const bf16x8*)(vh_s + a);
                bf16x8 vbl = *(const bf16x8*)(vl_s + a);
                #pragma unroll
                for (int mt = 0; mt < 2; ++mt) {
                    oacc[mt][dt] = __builtin_amdgcn_mfma_f32_16x16x32_bf16(pal[mt][cc], vbh, oacc[mt][dt], 0, 0, 0);
                    oacc[mt][dt] = __builtin_amdgcn_mfma_f32_16x16x32_bf16(pah[mt][cc], vbl, oacc[mt][dt], 0, 0, 0);
                    oacc[mt][dt] = __builtin_amdgcn_mfma_f32_16x16x32_bf16(pah[mt][cc], vbh, oacc[mt][dt], 0, 0, 0);
                }
            }
    }

    // deferred l reduction (across the 16 r-lanes of each quad)
    float inv_l[2][4];
    #pragma unroll
    for (int mt = 0; mt < 2; ++mt)
        #pragma unroll
        for (int v = 0; v < 4; ++v) {
            float l = l_part[mt][v];
            l += __shfl_xor(l, 1);
            l += __shfl_xor(l, 2);
            l += __shfl_xor(l, 4);
            l += __shfl_xor(l, 8);
            inv_l[mt][v] = 1.0f / l;
        }

    // epilogue: normalize + split into LDS [128][80] hi then lo, store uint4
    __syncthreads();
    #pragma unroll
    for (int mt = 0; mt < 2; ++mt)
        #pragma unroll
        for (int v = 0; v < 4; ++v) {
            int row = wave * 32 + mt * 16 + quad * 4 + v;
            #pragma unroll
            for (int dt = 0; dt < 5; ++dt) {
                float o = oacc[mt][dt][v] * inv_l[mt][v];
                ushort hh, ll;
                split2(o, hh, ll);
                lds[row * 80 + dt * 16 + r] = hh;
                lds[10240 + row * 80 + dt * 16 + r] = ll;
            }
        }
    __syncthreads();
    {
        size_t gbase = ((size_t)b * NN + q0) * HIDDEN + h * HD;
        #pragma unroll
        for (int i = 0; i < 10; ++i) {
            int u = tid + i * 256;            // 0..2559
            int plane = u / 1280, idx = u % 1280;
            int row = idx / 10, part = idx % 10;
            uint4 w = *(const uint4*)(lds + plane * 10240 + idx * 8);
            ushort* dst = (plane ? ao_lo : ao_hi) + gbase + (size_t)row * HIDDEN + part * 8;
            *(uint4*)dst = w;
        }
    }
}

// ---------------------------------------------------------------------------
extern "C" void kernel_launch(void* const* d_in, const int* in_sizes, int n_in,
                              void* d_out, int out_size, void* d_ws, size_t ws_size,
                              hipStream_t stream)
{
    const float* x      = (const float*)d_in[0];
    const float* cos_t  = (const float*)d_in[1];
    const float* sin_t  = (const float*)d_in[2];
    const float* qkv_w  = (const float*)d_in[3];
    const float* qkv_b  = (const float*)d_in[4];
    const float* proj_w = (const float*)d_in[5];
    const float* proj_b = (const float*)d_in[6];
    float* out = (float*)d_out;

    char* ws = (char*)d_ws;
    // layout (bytes), with phase-based reuse:
    //   [0, 62914560)           qkv fp32 (gemm1 out; dead after rope_split)
    //       -> ao_hi @ 0 (10485760), ao_lo @ 10485760 (attn out)
    //   [62914560, 82575360)    wT hi/lo for gemm1; after gemm1 reused:
    //       -> vt_hi @ 62914560 (10485760), vt_lo @ 73400320 (ends 83886080)
    //       -> re-written by tsplit(proj_w) AFTER attention for gemm2
    //   [82575360, 103546880)   a hi/lo (x split, gemm1 A); after gemm1:
    //       -> q_hi @ 83886080 (12582912), q_lo @ 96468992 (ends 109051904)
    //   [109051904, 134217728)  k_hi, k_lo ([bh][2048][96])
    float*  qkv   = (float*)ws;
    ushort* ao_hi = (ushort*)ws;
    ushort* ao_lo = (ushort*)(ws + 10485760);
    ushort* wT_hi = (ushort*)(ws + 62914560);
    ushort* wT_lo = (ushort*)(ws + 72744960);
    ushort* a_hi  = (ushort*)(ws + 82575360);
    ushort* a_lo  = (ushort*)(ws + 93061120);
    ushort* vt_hi = (ushort*)(ws + 62914560);
    ushort* vt_lo = (ushort*)(ws + 73400320);
    ushort* q_hi  = (ushort*)(ws + 83886080);
    ushort* q_lo  = (ushort*)(ws + 96468992);
    ushort* k_hi  = (ushort*)(ws + 109051904);
    ushort* k_lo  = (ushort*)(ws + 121634816);

    // 1) split x into bf16 hi/lo
    split_kernel<<<(MROWS * HIDDEN / 4 + 255) / 256, 256, 0, stream>>>(
        x, a_hi, a_lo, MROWS * HIDDEN / 4);

    // 2) transpose+split qkv_w
    tsplit_kernel<<<dim3(3 * HIDDEN / 32, HIDDEN / 32), 256, 0, stream>>>(
        qkv_w, wT_hi, wT_lo, HIDDEN, 3 * HIDDEN);

    // 3) qkv = x @ qkv_w + qkv_b
    gemm_bf16x3_kernel<<<dim3(3 * HIDDEN / BN, MROWS / BM), 256, 0, stream>>>(
        a_hi, a_lo, wT_hi, wT_lo, qkv_b, qkv, MROWS, 3 * HIDDEN, HIDDEN);

    // 4) RoPE + split + relayout (overwrites wT and a regions — both dead)
    rope_split_kernel<<<dim3(NN / 64, HEADS, BB), 256, 0, stream>>>(
        qkv, cos_t, sin_t, q_hi, q_lo, k_hi, k_lo, vt_hi, vt_lo);

    // 5) MFMA flash attention (ao overwrites qkv region — dead now)
    attn_mfma_kernel<<<dim3(NN / 128, HEADS, BB), 256, 0, stream>>>(
        q_hi, q_lo, k_hi, k_lo, vt_hi, vt_lo, ao_hi, ao_lo);

    // 6) transpose+split proj_w (overwrites vt region — dead after attn)
    tsplit_kernel<<<dim3(HIDDEN / 32, HIDDEN / 32), 256, 0, stream>>>(
        proj_w, wT_hi, wT_lo, HIDDEN, HIDDEN);

    // 7) out = attn_out @ proj_w + proj_b
    gemm_bf16x3_kernel<<<dim3(HIDDEN / BN, MROWS / BM), 256, 0, stream>>>(
        ao_hi, ao_lo, wT_hi, wT_lo, proj_b, out, MROWS, HIDDEN, HIDDEN);
}

// Round 7
// 424.929 us; speedup vs baseline: 4.0950x; 1.1615x over previous
//
#include <hip/hip_runtime.h>
#include <hip/hip_bf16.h>
#include <math.h>

#define HIDDEN 1280
#define HEADS 16
#define HD 80           // head dim
#define HALF 40
#define BB 2
#define NN 2048
#define MROWS (BB * NN) // 4096
// 1/sqrt(80) * log2(e): scores come out in log2 domain -> exp2 directly
#define QSCALE ((float)(0.11180339887498949 * 1.4426950408889634))

typedef __attribute__((ext_vector_type(8))) __bf16 bf16x8;
typedef __attribute__((ext_vector_type(8))) _Float16 f16x8;
typedef __attribute__((ext_vector_type(4))) float f32x4;

#define AS1 __attribute__((address_space(1)))
#define AS3 __attribute__((address_space(3)))

// Split fp32 into bf16 hi + bf16 lo (hi+lo carries ~16 mantissa bits).
__device__ __forceinline__ void split2(float x, ushort& hi, ushort& lo) {
    __hip_bfloat16 h = __float2bfloat16(x);
    float r = x - __bfloat162float(h);
    __hip_bfloat16 l = __float2bfloat16(r);
    hi = __builtin_bit_cast(ushort, h);
    lo = __builtin_bit_cast(ushort, l);
}

__device__ __forceinline__ ushort4 split4hi(float4 v, ushort4& lo4) {
    ushort4 h;
    split2(v.x, h.x, lo4.x);
    split2(v.y, h.y, lo4.y);
    split2(v.z, h.z, lo4.z);
    split2(v.w, h.w, lo4.w);
    return h;
}

__device__ __forceinline__ ushort f2h(float x) {
    _Float16 h = (_Float16)x;
    return __builtin_bit_cast(ushort, h);
}

// ---------------------------------------------------------------------------
// Elementwise split: fp32 [n] -> bf16 hi[n], lo[n]. 4 elems/thread.
// ---------------------------------------------------------------------------
__global__ __launch_bounds__(256) void split_kernel(
    const float* __restrict__ in, ushort* __restrict__ hi,
    ushort* __restrict__ lo, int n4)
{
    int i = blockIdx.x * 256 + threadIdx.x;
    if (i >= n4) return;
    float4 v = ((const float4*)in)[i];
    ushort4 h, l;
    h = split4hi(v, l);
    ((ushort4*)hi)[i] = h;
    ((ushort4*)lo)[i] = l;
}

// ---------------------------------------------------------------------------
// Transpose + split: W[K][N] fp32 -> WT_hi[N][K], WT_lo[N][K] bf16.
// ---------------------------------------------------------------------------
__global__ __launch_bounds__(256) void tsplit_kernel(
    const float* __restrict__ W, ushort* __restrict__ Thi,
    ushort* __restrict__ Tlo, int K, int N)
{
    __shared__ float s[32][33];
    const int n0 = blockIdx.x * 32;
    const int k0 = blockIdx.y * 32;
    {
        int tn = threadIdx.x & 31, tk = threadIdx.x >> 5;
        #pragma unroll
        for (int i = 0; i < 4; ++i)
            s[tk + i * 8][tn] = W[(size_t)(k0 + tk + i * 8) * N + n0 + tn];
    }
    __syncthreads();
    {
        int tk = threadIdx.x & 31, tn = threadIdx.x >> 5;
        #pragma unroll
        for (int i = 0; i < 4; ++i) {
            float v = s[tk][tn + i * 8];
            ushort h, l;
            split2(v, h, l);
            size_t o = (size_t)(n0 + tn + i * 8) * K + k0 + tk;
            Thi[o] = h;
            Tlo[o] = l;
        }
    }
}

// ---------------------------------------------------------------------------
// bf16x3 MFMA GEMM: C[M,N] = (Ahi+Alo)[M,K] @ (Bhi+Blo)[N,K]^T + bias[N]
// ---------------------------------------------------------------------------
#define BM 128
#define BN 128
#define BK 32

__global__ __launch_bounds__(256) void gemm_bf16x3_kernel(
    const ushort* __restrict__ Ahi, const ushort* __restrict__ Alo,
    const ushort* __restrict__ Bhi, const ushort* __restrict__ Blo,
    const float* __restrict__ bias, float* __restrict__ C,
    int M, int N, int K)
{
    __shared__ __align__(16) ushort lds[4 * 128 * 32];

    const int tid = threadIdx.x;
    const int wid = tid >> 6;
    const int lane = tid & 63;
    const int col0 = blockIdx.x * BN;
    const int row0 = blockIdx.y * BM;
    const int wy = wid >> 1, wx = wid & 1;

    const ushort* src = (wid == 0) ? Ahi : (wid == 1) ? Alo : (wid == 2) ? Bhi : Blo;
    const int srow = (wid < 2) ? row0 : col0;
    ushort* lbase = lds + wid * 4096;
    const int lrow = lane >> 2;
    const int lchunk = lane & 3;

    f32x4 acc[4][4] = {};

    for (int k0 = 0; k0 < K; k0 += BK) {
        __syncthreads();
        {
            const ushort* g0 = src + (size_t)(srow + lrow) * K + k0 + lchunk * 8;
            ushort* l0 = lbase + lane * 8;
            #pragma unroll
            for (int t = 0; t < 8; ++t) {
                __builtin_amdgcn_global_load_lds(
                    (const AS1 unsigned int*)(g0 + (size_t)t * 16 * K),
                    (AS3 unsigned int*)(l0 + t * 512),
                    16, 0, 0);
            }
        }
        __syncthreads();

        const int q = lane >> 4;
        const int r = lane & 15;
        bf16x8 ah[4], al[4], bh[4], bl[4];
        #pragma unroll
        for (int i = 0; i < 4; ++i) {
            int arow = wy * 64 + i * 16 + r;
            ah[i] = *(const bf16x8*)(lds + 0 * 4096 + arow * 32 + q * 8);
            al[i] = *(const bf16x8*)(lds + 1 * 4096 + arow * 32 + q * 8);
            int brow = wx * 64 + i * 16 + r;
            bh[i] = *(const bf16x8*)(lds + 2 * 4096 + brow * 32 + q * 8);
            bl[i] = *(const bf16x8*)(lds + 3 * 4096 + brow * 32 + q * 8);
        }
        #pragma unroll
        for (int i = 0; i < 4; ++i) {
            #pragma unroll
            for (int j = 0; j < 4; ++j) {
                acc[i][j] = __builtin_amdgcn_mfma_f32_16x16x32_bf16(al[i], bh[j], acc[i][j], 0, 0, 0);
                acc[i][j] = __builtin_amdgcn_mfma_f32_16x16x32_bf16(ah[i], bl[j], acc[i][j], 0, 0, 0);
                acc[i][j] = __builtin_amdgcn_mfma_f32_16x16x32_bf16(ah[i], bh[j], acc[i][j], 0, 0, 0);
            }
        }
    }

    const int q = lane >> 4, r = lane & 15;
    #pragma unroll
    for (int i = 0; i < 4; ++i) {
        #pragma unroll
        for (int j = 0; j < 4; ++j) {
            int col = col0 + wx * 64 + j * 16 + r;
            float b = bias[col];
            #pragma unroll
            for (int v = 0; v < 4; ++v) {
                int row = row0 + wy * 64 + i * 16 + q * 4 + v;
                C[(size_t)row * N + col] = acc[i][j][v] + b;
            }
        }
    }
}

// ---------------------------------------------------------------------------
// RoPE + scale + split + head-major relayout.
// Reads qkv fp32 (b,n,3,H,80). Writes:
//   q_hi/q_lo [bh][n][96] bf16 (RoPE'd, * QSCALE, d 80..95 zeroed)
//   k_hi/k_lo [bh][n][96] bf16 (RoPE'd, d 80..95 zeroed)
//   vt        [bh][80][2048] fp16 (V transposed, single plane)
// Grid (NN/64, HEADS, BB), 256 threads.
// ---------------------------------------------------------------------------
__global__ __launch_bounds__(256) void rope_split_kernel(
    const float* __restrict__ qkv, const float* __restrict__ cos_t,
    const float* __restrict__ sin_t,
    ushort* __restrict__ q_hi, ushort* __restrict__ q_lo,
    ushort* __restrict__ k_hi, ushort* __restrict__ k_lo,
    ushort* __restrict__ vt)
{
    __shared__ float s_v[64][84];
    const int tid = threadIdx.x;
    const int b = blockIdx.z, h = blockIdx.y;
    const int n0 = blockIdx.x * 64;
    const int bh = b * HEADS + h;

    // V tile -> LDS (coalesced float4 loads)
    #pragma unroll
    for (int i = 0; i < 5; ++i) {
        int u = tid + i * 256;
        int n = u / 20, c = u % 20;
        const float* src = qkv + (size_t)(b * NN + n0 + n) * 3840 + 2 * HIDDEN + h * HD + c * 4;
        *(float4*)(&s_v[n][c * 4]) = *(const float4*)src;
    }

    // q,k RoPE + split: 640 units, each = (token n, 4-wide d group in [0,40))
    for (int u = tid; u < 640; u += 256) {
        int n = u / 10, p = u % 10;
        int d = p * 4;
        int ng = n0 + n;
        size_t rowb = (size_t)(b * NN + ng) * 3840;
        float4 c0 = *(const float4*)(cos_t + ng * HD + d);
        float4 c1 = *(const float4*)(cos_t + ng * HD + d + HALF);
        float4 s0 = *(const float4*)(sin_t + ng * HD + d);
        float4 s1 = *(const float4*)(sin_t + ng * HD + d + HALF);
        size_t qo = ((size_t)bh * NN + ng) * 96;
        // q (scaled by QSCALE so scores are in log2 domain)
        {
            float4 x0 = *(const float4*)(qkv + rowb + h * HD + d);
            float4 x1 = *(const float4*)(qkv + rowb + h * HD + d + HALF);
            float4 o0, o1;
            o0.x = (x0.x * c0.x - x1.x * s0.x) * QSCALE;
            o0.y = (x0.y * c0.y - x1.y * s0.y) * QSCALE;
            o0.z = (x0.z * c0.z - x1.z * s0.z) * QSCALE;
            o0.w = (x0.w * c0.w - x1.w * s0.w) * QSCALE;
            o1.x = (x1.x * c1.x + x0.x * s1.x) * QSCALE;
            o1.y = (x1.y * c1.y + x0.y * s1.y) * QSCALE;
            o1.z = (x1.z * c1.z + x0.z * s1.z) * QSCALE;
            o1.w = (x1.w * c1.w + x0.w * s1.w) * QSCALE;
            ushort4 h4, l4;
            h4 = split4hi(o0, l4);
            *(ushort4*)(q_hi + qo + d) = h4;
            *(ushort4*)(q_lo + qo + d) = l4;
            h4 = split4hi(o1, l4);
            *(ushort4*)(q_hi + qo + d + HALF) = h4;
            *(ushort4*)(q_lo + qo + d + HALF) = l4;
        }
        // k (unscaled)
        {
            float4 x0 = *(const float4*)(qkv + rowb + HIDDEN + h * HD + d);
            float4 x1 = *(const float4*)(qkv + rowb + HIDDEN + h * HD + d + HALF);
            float4 o0, o1;
            o0.x = x0.x * c0.x - x1.x * s0.x;
            o0.y = x0.y * c0.y - x1.y * s0.y;
            o0.z = x0.z * c0.z - x1.z * s0.z;
            o0.w = x0.w * c0.w - x1.w * s0.w;
            o1.x = x1.x * c1.x + x0.x * s1.x;
            o1.y = x1.y * c1.y + x0.y * s1.y;
            o1.z = x1.z * c1.z + x0.z * s1.z;
            o1.w = x1.w * c1.w + x0.w * s1.w;
            ushort4 h4, l4;
            h4 = split4hi(o0, l4);
            *(ushort4*)(k_hi + qo + d) = h4;
            *(ushort4*)(k_lo + qo + d) = l4;
            h4 = split4hi(o1, l4);
            *(ushort4*)(k_hi + qo + d + HALF) = h4;
            *(ushort4*)(k_lo + qo + d + HALF) = l4;
        }
    }

    // zero the d=80..95 pad for q and k (both planes). 256 units exactly.
    {
        int n = tid >> 2;
        int which = (tid >> 1) & 1;
        int cpart = tid & 1;
        size_t o = ((size_t)bh * NN + n0 + n) * 96 + 80 + cpart * 8;
        uint4 z = {0u, 0u, 0u, 0u};
        if (which == 0) {
            *(uint4*)(q_hi + o) = z;
            *(uint4*)(q_lo + o) = z;
        } else {
            *(uint4*)(k_hi + o) = z;
            *(uint4*)(k_lo + o) = z;
        }
    }
    __syncthreads();

    // V^T write (fp16 single plane): unit = (d, 16-token chunk)
    for (int u = tid; u < 320; u += 256) {
        int d = u >> 2, nc = u & 3;
        ushort hs[16];
        #pragma unroll
        for (int kk = 0; kk < 16; ++kk)
            hs[kk] = f2h(s_v[nc * 16 + kk][d]);
        size_t o = ((size_t)bh * HD + d) * NN + n0 + nc * 16;
        uint4 w0, w1;
        w0.x = (uint)hs[0] | ((uint)hs[1] << 16);
        w0.y = (uint)hs[2] | ((uint)hs[3] << 16);
        w0.z = (uint)hs[4] | ((uint)hs[5] << 16);
        w0.w = (uint)hs[6] | ((uint)hs[7] << 16);
        w1.x = (uint)hs[8] | ((uint)hs[9] << 16);
        w1.y = (uint)hs[10] | ((uint)hs[11] << 16);
        w1.z = (uint)hs[12] | ((uint)hs[13] << 16);
        w1.w = (uint)hs[14] | ((uint)hs[15] << 16);
        *(uint4*)(vt + o) = w0;
        *(uint4*)(vt + o + 8) = w1;
    }
}

// ---------------------------------------------------------------------------
// MFMA flash attention v2.1 (round-5 structure, verified 16x16x32 layouts):
//  - QK^T: 16x16x32 bf16x3 over 96-wide padded K (round-5 verbatim).
//  - PV: 16x16x32 fp16 single-term (P, V fp16; fp32 acc). Same swizzle
//    pairs round 5 validated end-to-end.
//  - no-max softmax (exp2, log2-domain scores), deferred l reduction.
//  - LDS 51200 B (single-buffered K/V).
// ---------------------------------------------------------------------------
__global__ __launch_bounds__(256, 2) void attn_mfma_kernel(
    const ushort* __restrict__ q_hi, const ushort* __restrict__ q_lo,
    const ushort* __restrict__ k_hi, const ushort* __restrict__ k_lo,
    const ushort* __restrict__ vt,
    ushort* __restrict__ ao_hi, ushort* __restrict__ ao_lo)
{
    __shared__ __align__(16) ushort lds[25600];   // 51200 B
    ushort* kh_s = lds;                           // [64][96] = 6144
    ushort* kl_s = lds + 6144;
    _Float16* v_s = (_Float16*)(lds + 12288);     // [80][64] chunk-swizzled
    _Float16* p_s = (_Float16*)(lds + 17408);     // [128][64] block-swizzled

    const int tid = threadIdx.x;
    const int wave = tid >> 6, lane = tid & 63;
    const int quad = lane >> 4, r = lane & 15;
    const int b = blockIdx.z, h = blockIdx.y;
    const int bh = b * HEADS + h;
    const int q0 = blockIdx.x * 128;

    // Q a-frags from [bh][n][96] (pre-scaled by QSCALE, pad zero)
    bf16x8 qfh[2][3], qfl[2][3];
    #pragma unroll
    for (int mt = 0; mt < 2; ++mt)
        #pragma unroll
        for (int c = 0; c < 3; ++c) {
            size_t o = ((size_t)bh * NN + q0 + wave * 32 + mt * 16 + r) * 96 + c * 32 + quad * 8;
            qfh[mt][c] = *(const bf16x8*)(q_hi + o);
            qfl[mt][c] = *(const bf16x8*)(q_lo + o);
        }

    f32x4 oacc[2][5] = {};
    float l_part[2][4] = {};

    const size_t kb = (size_t)bh * NN * 96;
    const size_t vb = (size_t)bh * HD * NN;

    for (int j0 = 0; j0 < NN; j0 += 64) {
        __syncthreads();
        // stage K hi/lo (12 segs each, linear) + V^T fp16 (10 segs, swizzled)
        for (int s = wave; s < 34; s += 4) {
            if (s < 24) {
                const ushort* gp = (s < 12 ? k_hi : k_lo);
                ushort* lp = (s < 12 ? kh_s : kl_s);
                int seg = (s < 12) ? s : s - 12;
                int off = seg * 512 + lane * 8;
                __builtin_amdgcn_global_load_lds(
                    (const AS1 unsigned int*)(gp + kb + (size_t)j0 * 96 + off),
                    (AS3 unsigned int*)(lp + off), 16, 0, 0);
            } else {
                int ts = s - 24;
                int off = ts * 512 + lane * 8;
                size_t go = vb + (size_t)(ts * 8 + (lane >> 3)) * NN + j0
                          + (size_t)(((lane & 7) ^ (lane >> 3)) * 8);
                __builtin_amdgcn_global_load_lds(
                    (const AS1 unsigned int*)(vt + go),
                    (AS3 unsigned int*)((ushort*)v_s + off), 16, 0, 0);
            }
        }
        __syncthreads();

        // QK^T -> scores in C-layout (log2 domain)
        f32x4 sc[2][4] = {};
        #pragma unroll
        for (int jt = 0; jt < 4; ++jt) {
            bf16x8 kbh[3], kbl[3];
            int j = jt * 16 + r;
            #pragma unroll
            for (int c = 0; c < 3; ++c) {
                int a = j * 96 + c * 32 + quad * 8;
                kbh[c] = *(const bf16x8*)(kh_s + a);
                kbl[c] = *(const bf16x8*)(kl_s + a);
            }
            #pragma unroll
            for (int mt = 0; mt < 2; ++mt)
                #pragma unroll
                for (int c = 0; c < 3; ++c) {
                    sc[mt][jt] = __builtin_amdgcn_mfma_f32_16x16x32_bf16(qfl[mt][c], kbh[c], sc[mt][jt], 0, 0, 0);
                    sc[mt][jt] = __builtin_amdgcn_mfma_f32_16x16x32_bf16(qfh[mt][c], kbl[c], sc[mt][jt], 0, 0, 0);
                    sc[mt][jt] = __builtin_amdgcn_mfma_f32_16x16x32_bf16(qfh[mt][c], kbh[c], sc[mt][jt], 0, 0, 0);
                }
        }

        // no-max softmax: p = exp2(s); P -> LDS fp16 (swizzled); l partials
        #pragma unroll
        for (int mt = 0; mt < 2; ++mt) {
            #pragma unroll
            for (int v = 0; v < 4; ++v) {
                float ps = 0.0f;
                #pragma unroll
                for (int jt = 0; jt < 4; ++jt) {
                    float p = __builtin_amdgcn_exp2f(sc[mt][jt][v]);
                    sc[mt][jt][v] = p;
                    ps += p;
                }
                l_part[mt][v] += ps;
            }
            int rowbase = wave * 32 + mt * 16 + quad * 4;
            #pragma unroll
            for (int jt = 0; jt < 4; ++jt) {
                int bks = (jt * 2 + (r >> 3)) ^ (quad << 1);
                #pragma unroll
                for (int v = 0; v < 4; ++v)
                    p_s[(rowbase + v) * 64 + bks * 8 + (r & 7)] = (_Float16)sc[mt][jt][v];
            }
        }

        // P a-frags (wave-private rows, swizzled reads — round-5 pair)
        f16x8 pa[2][2];
        #pragma unroll
        for (int mt = 0; mt < 2; ++mt)
            #pragma unroll
            for (int cc = 0; cc < 2; ++cc) {
                int rowp = wave * 32 + mt * 16 + r;
                int bks = (cc * 4 + quad) ^ (((r >> 2) & 3) << 1);
                pa[mt][cc] = *(const f16x8*)(p_s + rowp * 64 + bks * 8);
            }

        // PV with V^T b-frags (chunk-swizzled reads — round-5 pair)
        #pragma unroll
        for (int dt = 0; dt < 5; ++dt)
            #pragma unroll
            for (int cc = 0; cc < 2; ++cc) {
                int ck = (cc * 4 + quad) ^ (r & 7);
                f16x8 vbf = *(const f16x8*)(v_s + (dt * 16 + r) * 64 + ck * 8);
                oacc[0][dt] = __builtin_amdgcn_mfma_f32_16x16x32_f16(pa[0][cc], vbf, oacc[0][dt], 0, 0, 0);
                oacc[1][dt] = __builtin_amdgcn_mfma_f32_16x16x32_f16(pa[1][cc], vbf, oacc[1][dt], 0, 0, 0);
            }
    }

    // deferred l reduction (across the 16 r-lanes of each quad)
    float inv_l[2][4];
    #pragma unroll
    for (int mt = 0; mt < 2; ++mt)
        #pragma unroll
        for (int v = 0; v < 4; ++v) {
            float l = l_part[mt][v];
            l += __shfl_xor(l, 1);
            l += __shfl_xor(l, 2);
            l += __shfl_xor(l, 4);
            l += __shfl_xor(l, 8);
            inv_l[mt][v] = 1.0f / l;
        }

    // epilogue: normalize + split into LDS [128][80] hi then lo, store uint4
    __syncthreads();
    #pragma unroll
    for (int mt = 0; mt < 2; ++mt)
        #pragma unroll
        for (int v = 0; v < 4; ++v) {
            int row = wave * 32 + mt * 16 + quad * 4 + v;
            #pragma unroll
            for (int dt = 0; dt < 5; ++dt) {
                float o = oacc[mt][dt][v] * inv_l[mt][v];
                ushort hh, ll;
                split2(o, hh, ll);
                lds[row * 80 + dt * 16 + r] = hh;
                lds[10240 + row * 80 + dt * 16 + r] = ll;
            }
        }
    __syncthreads();
    {
        size_t gbase = ((size_t)b * NN + q0) * HIDDEN + h * HD;
        #pragma unroll
        for (int i = 0; i < 10; ++i) {
            int u = tid + i * 256;            // 0..2559
            int plane = u / 1280, idx = u % 1280;
            int row = idx / 10, part = idx % 10;
            uint4 w = *(const uint4*)(lds + plane * 10240 + idx * 8);
            ushort* dst = (plane ? ao_lo : ao_hi) + gbase + (size_t)row * HIDDEN + part * 8;
            *(uint4*)dst = w;
        }
    }
}

// ---------------------------------------------------------------------------
extern "C" void kernel_launch(void* const* d_in, const int* in_sizes, int n_in,
                              void* d_out, int out_size, void* d_ws, size_t ws_size,
                              hipStream_t stream)
{
    const float* x      = (const float*)d_in[0];
    const float* cos_t  = (const float*)d_in[1];
    const float* sin_t  = (const float*)d_in[2];
    const float* qkv_w  = (const float*)d_in[3];
    const float* qkv_b  = (const float*)d_in[4];
    const float* proj_w = (const float*)d_in[5];
    const float* proj_b = (const float*)d_in[6];
    float* out = (float*)d_out;

    char* ws = (char*)d_ws;
    // layout (bytes), phase-based reuse (same footprint as round 5, 134217728):
    //   [0, 62914560)            qkv fp32 (gemm1 out; dead after rope_split)
    //       -> ao_hi @0 (10485760), ao_lo @10485760 (attn out)
    //   [62914560, 82575360)     wT hi/lo (gemm1 weights); after gemm1:
    //       -> vt fp16 @62914560 (10485760)
    //       -> re-written by tsplit(proj_w) AFTER attention for gemm2
    //   [82575360, 103546880)    a hi/lo (x split, gemm1 A); after gemm1:
    //       -> q_hi @83886080 (12582912), q_lo @96468992
    //   [109051904, 134217728)   k_hi, k_lo ([bh][2048][96])
    float*  qkv   = (float*)ws;
    ushort* ao_hi = (ushort*)ws;
    ushort* ao_lo = (ushort*)(ws + 10485760);
    ushort* wT_hi = (ushort*)(ws + 62914560);
    ushort* wT_lo = (ushort*)(ws + 72744960);
    ushort* vt    = (ushort*)(ws + 62914560);
    ushort* a_hi  = (ushort*)(ws + 82575360);
    ushort* a_lo  = (ushort*)(ws + 93061120);
    ushort* q_hi  = (ushort*)(ws + 83886080);
    ushort* q_lo  = (ushort*)(ws + 96468992);
    ushort* k_hi  = (ushort*)(ws + 109051904);
    ushort* k_lo  = (ushort*)(ws + 121634816);

    // 1) split x into bf16 hi/lo
    split_kernel<<<(MROWS * HIDDEN / 4 + 255) / 256, 256, 0, stream>>>(
        x, a_hi, a_lo, MROWS * HIDDEN / 4);

    // 2) transpose+split qkv_w
    tsplit_kernel<<<dim3(3 * HIDDEN / 32, HIDDEN / 32), 256, 0, stream>>>(
        qkv_w, wT_hi, wT_lo, HIDDEN, 3 * HIDDEN);

    // 3) qkv = x @ qkv_w + qkv_b
    gemm_bf16x3_kernel<<<dim3(3 * HIDDEN / BN, MROWS / BM), 256, 0, stream>>>(
        a_hi, a_lo, wT_hi, wT_lo, qkv_b, qkv, MROWS, 3 * HIDDEN, HIDDEN);

    // 4) RoPE + split + relayout (overwrites wT and a regions — both dead)
    rope_split_kernel<<<dim3(NN / 64, HEADS, BB), 256, 0, stream>>>(
        qkv, cos_t, sin_t, q_hi, q_lo, k_hi, k_lo, vt);

    // 5) MFMA flash attention (ao overwrites qkv region — dead now)
    attn_mfma_kernel<<<dim3(NN / 128, HEADS, BB), 256, 0, stream>>>(
        q_hi, q_lo, k_hi, k_lo, vt, ao_hi, ao_lo);

    // 6) transpose+split proj_w (overwrites vt region — dead after attn)
    tsplit_kernel<<<dim3(HIDDEN / 32, HIDDEN / 32), 256, 0, stream>>>(
        proj_w, wT_hi, wT_lo, HIDDEN, HIDDEN);

    // 7) out = attn_out @ proj_w + proj_b
    gemm_bf16x3_kernel<<<dim3(HIDDEN / BN, MROWS / BM), 256, 0, stream>>>(
        ao_hi, ao_lo, wT_hi, wT_lo, proj_b, out, MROWS, HIDDEN, HIDDEN);
}

// Round 8
// 357.424 us; speedup vs baseline: 4.8684x; 1.1889x over previous
//
#include <hip/hip_runtime.h>
#include <hip/hip_bf16.h>
#include <math.h>

#define HIDDEN 1280
#define HEADS 16
#define HD 80           // head dim
#define HALF 40
#define BB 2
#define NN 2048
#define MROWS (BB * NN) // 4096
// 1/sqrt(80) * log2(e): scores come out in log2 domain -> exp2 directly
#define QSCALE ((float)(0.11180339887498949 * 1.4426950408889634))

typedef __attribute__((ext_vector_type(8))) _Float16 f16x8;
typedef __attribute__((ext_vector_type(4))) float f32x4;

#define AS1 __attribute__((address_space(1)))
#define AS3 __attribute__((address_space(3)))

// Split fp32 into fp16 hi + fp16 lo (hi+lo carries ~22 mantissa bits).
__device__ __forceinline__ void splitf16(float x, ushort& hi, ushort& lo) {
    _Float16 h = (_Float16)x;
    _Float16 l = (_Float16)(x - (float)h);
    hi = __builtin_bit_cast(ushort, h);
    lo = __builtin_bit_cast(ushort, l);
}

__device__ __forceinline__ ushort f2h(float x) {
    _Float16 h = (_Float16)x;
    return __builtin_bit_cast(ushort, h);
}

// ---------------------------------------------------------------------------
// Elementwise split: fp32 [n] -> fp16 hi[n], lo[n]. 4 elems/thread.
// ---------------------------------------------------------------------------
__global__ __launch_bounds__(256) void split_f16_kernel(
    const float* __restrict__ in, ushort* __restrict__ hi,
    ushort* __restrict__ lo, int n4)
{
    int i = blockIdx.x * 256 + threadIdx.x;
    if (i >= n4) return;
    float4 v = ((const float4*)in)[i];
    ushort4 h, l;
    splitf16(v.x, h.x, l.x);
    splitf16(v.y, h.y, l.y);
    splitf16(v.z, h.z, l.z);
    splitf16(v.w, h.w, l.w);
    ((ushort4*)hi)[i] = h;
    ((ushort4*)lo)[i] = l;
}

// ---------------------------------------------------------------------------
// Transpose to fp16: W[K][N] fp32 -> WT[N][K] fp16 (single plane).
// ---------------------------------------------------------------------------
__global__ __launch_bounds__(256) void tsplit_f16_kernel(
    const float* __restrict__ W, ushort* __restrict__ T, int K, int N)
{
    __shared__ float s[32][33];
    const int n0 = blockIdx.x * 32;
    const int k0 = blockIdx.y * 32;
    {
        int tn = threadIdx.x & 31, tk = threadIdx.x >> 5;
        #pragma unroll
        for (int i = 0; i < 4; ++i)
            s[tk + i * 8][tn] = W[(size_t)(k0 + tk + i * 8) * N + n0 + tn];
    }
    __syncthreads();
    {
        int tk = threadIdx.x & 31, tn = threadIdx.x >> 5;
        #pragma unroll
        for (int i = 0; i < 4; ++i)
            T[(size_t)(n0 + tn + i * 8) * K + k0 + tk] = f2h(s[tk][tn + i * 8]);
    }
}

// ---------------------------------------------------------------------------
// fp16x2 MFMA GEMM: C[M,N] = (Ahi+Alo)[M,K] @ B[N,K]^T + bias[N]
// 2 MFMAs per tile: Al*B + Ah*B. Dropped Ah*Bl term ~2e-4 rms.
// 128x128 tile, BK=32, 4 waves, 3 staged tiles (Ah, Al, B).
// ---------------------------------------------------------------------------
#define BM 128
#define BN 128
#define BK 32

__global__ __launch_bounds__(256) void gemm_f16x2_kernel(
    const ushort* __restrict__ Ahi, const ushort* __restrict__ Alo,
    const ushort* __restrict__ Bh,
    const float* __restrict__ bias, float* __restrict__ C,
    int M, int N, int K)
{
    __shared__ __align__(16) ushort lds[3 * 128 * 32];   // 24 KB

    const int tid = threadIdx.x;
    const int wid = tid >> 6;
    const int lane = tid & 63;
    const int col0 = blockIdx.x * BN;
    const int row0 = blockIdx.y * BM;
    const int wy = wid >> 1, wx = wid & 1;
    const int lrow = lane >> 2;
    const int lchunk = lane & 3;

    f32x4 acc[4][4] = {};

    for (int k0 = 0; k0 < K; k0 += BK) {
        __syncthreads();
        // 24 segments (3 tiles x 8), 6 per wave
        #pragma unroll
        for (int i = 0; i < 6; ++i) {
            int s = wid + i * 4;
            int tile = s >> 3, t = s & 7;
            const ushort* src = (tile == 0) ? Ahi : (tile == 1) ? Alo : Bh;
            int srow = (tile < 2) ? row0 : col0;
            const ushort* g = src + (size_t)(srow + t * 16 + lrow) * K + k0 + lchunk * 8;
            ushort* l = lds + tile * 4096 + t * 512 + lane * 8;
            __builtin_amdgcn_global_load_lds(
                (const AS1 unsigned int*)g, (AS3 unsigned int*)l, 16, 0, 0);
        }
        __syncthreads();

        const int q = lane >> 4;
        const int r = lane & 15;
        f16x8 ah[4], al[4], bf[4];
        #pragma unroll
        for (int i = 0; i < 4; ++i) {
            int arow = wy * 64 + i * 16 + r;
            ah[i] = *(const f16x8*)(lds + 0 * 4096 + arow * 32 + q * 8);
            al[i] = *(const f16x8*)(lds + 1 * 4096 + arow * 32 + q * 8);
            int brow = wx * 64 + i * 16 + r;
            bf[i] = *(const f16x8*)(lds + 2 * 4096 + brow * 32 + q * 8);
        }
        #pragma unroll
        for (int i = 0; i < 4; ++i) {
            #pragma unroll
            for (int j = 0; j < 4; ++j) {
                acc[i][j] = __builtin_amdgcn_mfma_f32_16x16x32_f16(al[i], bf[j], acc[i][j], 0, 0, 0);
                acc[i][j] = __builtin_amdgcn_mfma_f32_16x16x32_f16(ah[i], bf[j], acc[i][j], 0, 0, 0);
            }
        }
    }

    const int q = lane >> 4, r = lane & 15;
    #pragma unroll
    for (int i = 0; i < 4; ++i) {
        #pragma unroll
        for (int j = 0; j < 4; ++j) {
            int col = col0 + wx * 64 + j * 16 + r;
            float b = bias[col];
            #pragma unroll
            for (int v = 0; v < 4; ++v) {
                int row = row0 + wy * 64 + i * 16 + q * 4 + v;
                C[(size_t)row * N + col] = acc[i][j][v] + b;
            }
        }
    }
}

// ---------------------------------------------------------------------------
// RoPE + scale + fp16 convert + head-major relayout.
// Reads qkv fp32 (b,n,3,H,80). Writes:
//   qf [bh][n][96] fp16 (RoPE'd, * QSCALE, d 80..95 zeroed)
//   kf [bh][n][96] fp16 (RoPE'd, d 80..95 zeroed)
//   vt [bh][80][2048] fp16 (V transposed)
// Grid (NN/64, HEADS, BB), 256 threads.
// ---------------------------------------------------------------------------
__global__ __launch_bounds__(256) void rope_split_kernel(
    const float* __restrict__ qkv, const float* __restrict__ cos_t,
    const float* __restrict__ sin_t,
    ushort* __restrict__ qf, ushort* __restrict__ kf,
    ushort* __restrict__ vt)
{
    __shared__ float s_v[64][84];
    const int tid = threadIdx.x;
    const int b = blockIdx.z, h = blockIdx.y;
    const int n0 = blockIdx.x * 64;
    const int bh = b * HEADS + h;

    // V tile -> LDS (coalesced float4 loads)
    #pragma unroll
    for (int i = 0; i < 5; ++i) {
        int u = tid + i * 256;
        int n = u / 20, c = u % 20;
        const float* src = qkv + (size_t)(b * NN + n0 + n) * 3840 + 2 * HIDDEN + h * HD + c * 4;
        *(float4*)(&s_v[n][c * 4]) = *(const float4*)src;
    }

    // q,k RoPE + fp16: 640 units, each = (token n, 4-wide d group in [0,40))
    for (int u = tid; u < 640; u += 256) {
        int n = u / 10, p = u % 10;
        int d = p * 4;
        int ng = n0 + n;
        size_t rowb = (size_t)(b * NN + ng) * 3840;
        float4 c0 = *(const float4*)(cos_t + ng * HD + d);
        float4 c1 = *(const float4*)(cos_t + ng * HD + d + HALF);
        float4 s0 = *(const float4*)(sin_t + ng * HD + d);
        float4 s1 = *(const float4*)(sin_t + ng * HD + d + HALF);
        size_t qo = ((size_t)bh * NN + ng) * 96;
        // q (scaled by QSCALE so scores are in log2 domain)
        {
            float4 x0 = *(const float4*)(qkv + rowb + h * HD + d);
            float4 x1 = *(const float4*)(qkv + rowb + h * HD + d + HALF);
            ushort4 h4a, h4b;
            h4a.x = f2h((x0.x * c0.x - x1.x * s0.x) * QSCALE);
            h4a.y = f2h((x0.y * c0.y - x1.y * s0.y) * QSCALE);
            h4a.z = f2h((x0.z * c0.z - x1.z * s0.z) * QSCALE);
            h4a.w = f2h((x0.w * c0.w - x1.w * s0.w) * QSCALE);
            h4b.x = f2h((x1.x * c1.x + x0.x * s1.x) * QSCALE);
            h4b.y = f2h((x1.y * c1.y + x0.y * s1.y) * QSCALE);
            h4b.z = f2h((x1.z * c1.z + x0.z * s1.z) * QSCALE);
            h4b.w = f2h((x1.w * c1.w + x0.w * s1.w) * QSCALE);
            *(ushort4*)(qf + qo + d) = h4a;
            *(ushort4*)(qf + qo + d + HALF) = h4b;
        }
        // k (unscaled)
        {
            float4 x0 = *(const float4*)(qkv + rowb + HIDDEN + h * HD + d);
            float4 x1 = *(const float4*)(qkv + rowb + HIDDEN + h * HD + d + HALF);
            ushort4 h4a, h4b;
            h4a.x = f2h(x0.x * c0.x - x1.x * s0.x);
            h4a.y = f2h(x0.y * c0.y - x1.y * s0.y);
            h4a.z = f2h(x0.z * c0.z - x1.z * s0.z);
            h4a.w = f2h(x0.w * c0.w - x1.w * s0.w);
            h4b.x = f2h(x1.x * c1.x + x0.x * s1.x);
            h4b.y = f2h(x1.y * c1.y + x0.y * s1.y);
            h4b.z = f2h(x1.z * c1.z + x0.z * s1.z);
            h4b.w = f2h(x1.w * c1.w + x0.w * s1.w);
            *(ushort4*)(kf + qo + d) = h4a;
            *(ushort4*)(kf + qo + d + HALF) = h4b;
        }
    }

    // zero the d=80..95 pad for q and k. 256 units: which(1b) x n(6b) x part(1b)
    {
        int which = tid >> 7;
        int u = tid & 127;
        int n = u >> 1, part = u & 1;
        size_t o = ((size_t)bh * NN + n0 + n) * 96 + 80 + part * 8;
        uint4 z = {0u, 0u, 0u, 0u};
        if (which == 0) *(uint4*)(qf + o) = z;
        else            *(uint4*)(kf + o) = z;
    }
    __syncthreads();

    // V^T write (fp16): unit = (d, 16-token chunk)
    for (int u = tid; u < 320; u += 256) {
        int d = u >> 2, nc = u & 3;
        ushort hs[16];
        #pragma unroll
        for (int kk = 0; kk < 16; ++kk)
            hs[kk] = f2h(s_v[nc * 16 + kk][d]);
        size_t o = ((size_t)bh * HD + d) * NN + n0 + nc * 16;
        uint4 w0, w1;
        w0.x = (uint)hs[0] | ((uint)hs[1] << 16);
        w0.y = (uint)hs[2] | ((uint)hs[3] << 16);
        w0.z = (uint)hs[4] | ((uint)hs[5] << 16);
        w0.w = (uint)hs[6] | ((uint)hs[7] << 16);
        w1.x = (uint)hs[8] | ((uint)hs[9] << 16);
        w1.y = (uint)hs[10] | ((uint)hs[11] << 16);
        w1.z = (uint)hs[12] | ((uint)hs[13] << 16);
        w1.w = (uint)hs[14] | ((uint)hs[15] << 16);
        *(uint4*)(vt + o) = w0;
        *(uint4*)(vt + o + 8) = w1;
    }
}

// ---------------------------------------------------------------------------
// MFMA flash attention v4 (round-7 structure, fp16 single-term QK):
//  - QK^T: 16x16x32 fp16 x1 over 96-wide padded K (QSCALE baked into q).
//  - PV: 16x16x32 fp16 x1 (round-7 validated swizzle pairs).
//  - no-max softmax (exp2, log2-domain scores), deferred l reduction.
//  - LDS 40960 B.
// ---------------------------------------------------------------------------
__global__ __launch_bounds__(256, 2) void attn_mfma_kernel(
    const ushort* __restrict__ qf, const ushort* __restrict__ kf,
    const ushort* __restrict__ vt,
    ushort* __restrict__ ao_hi, ushort* __restrict__ ao_lo)
{
    __shared__ __align__(16) ushort lds[20480];   // 40960 B
    ushort* k_s = lds;                            // [64][96] = 6144
    _Float16* v_s = (_Float16*)(lds + 6144);      // [80][64] chunk-swizzled
    _Float16* p_s = (_Float16*)(lds + 11264);     // [128][64] block-swizzled

    const int tid = threadIdx.x;
    const int wave = tid >> 6, lane = tid & 63;
    const int quad = lane >> 4, r = lane & 15;
    const int b = blockIdx.z, h = blockIdx.y;
    const int bh = b * HEADS + h;
    const int q0 = blockIdx.x * 128;

    // Q a-frags from [bh][n][96] fp16 (pre-scaled by QSCALE, pad zero)
    f16x8 qfr[2][3];
    #pragma unroll
    for (int mt = 0; mt < 2; ++mt)
        #pragma unroll
        for (int c = 0; c < 3; ++c) {
            size_t o = ((size_t)bh * NN + q0 + wave * 32 + mt * 16 + r) * 96 + c * 32 + quad * 8;
            qfr[mt][c] = *(const f16x8*)(qf + o);
        }

    f32x4 oacc[2][5] = {};
    float l_part[2][4] = {};

    const size_t kb = (size_t)bh * NN * 96;
    const size_t vb = (size_t)bh * HD * NN;

    for (int j0 = 0; j0 < NN; j0 += 64) {
        __syncthreads();
        // stage K fp16 (12 segs, linear) + V^T fp16 (10 segs, src-swizzled)
        for (int s = wave; s < 22; s += 4) {
            if (s < 12) {
                int off = s * 512 + lane * 8;
                __builtin_amdgcn_global_load_lds(
                    (const AS1 unsigned int*)(kf + kb + (size_t)j0 * 96 + off),
                    (AS3 unsigned int*)(k_s + off), 16, 0, 0);
            } else {
                int ts = s - 12;
                int off = ts * 512 + lane * 8;
                size_t go = vb + (size_t)(ts * 8 + (lane >> 3)) * NN + j0
                          + (size_t)(((lane & 7) ^ (lane >> 3)) * 8);
                __builtin_amdgcn_global_load_lds(
                    (const AS1 unsigned int*)(vt + go),
                    (AS3 unsigned int*)((ushort*)v_s + off), 16, 0, 0);
            }
        }
        __syncthreads();

        // QK^T -> scores in C-layout (log2 domain), single fp16 term
        f32x4 sc[2][4] = {};
        #pragma unroll
        for (int jt = 0; jt < 4; ++jt) {
            f16x8 kbf[3];
            int j = jt * 16 + r;
            #pragma unroll
            for (int c = 0; c < 3; ++c)
                kbf[c] = *(const f16x8*)(k_s + j * 96 + c * 32 + quad * 8);
            #pragma unroll
            for (int mt = 0; mt < 2; ++mt)
                #pragma unroll
                for (int c = 0; c < 3; ++c)
                    sc[mt][jt] = __builtin_amdgcn_mfma_f32_16x16x32_f16(qfr[mt][c], kbf[c], sc[mt][jt], 0, 0, 0);
        }

        // no-max softmax: p = exp2(s); P -> LDS fp16 (swizzled); l partials
        #pragma unroll
        for (int mt = 0; mt < 2; ++mt) {
            #pragma unroll
            for (int v = 0; v < 4; ++v) {
                float ps = 0.0f;
                #pragma unroll
                for (int jt = 0; jt < 4; ++jt) {
                    float p = __builtin_amdgcn_exp2f(sc[mt][jt][v]);
                    sc[mt][jt][v] = p;
                    ps += p;
                }
                l_part[mt][v] += ps;
            }
            int rowbase = wave * 32 + mt * 16 + quad * 4;
            #pragma unroll
            for (int jt = 0; jt < 4; ++jt) {
                int bks = (jt * 2 + (r >> 3)) ^ (quad << 1);
                #pragma unroll
                for (int v = 0; v < 4; ++v)
                    p_s[(rowbase + v) * 64 + bks * 8 + (r & 7)] = (_Float16)sc[mt][jt][v];
            }
        }

        // P a-frags (wave-private rows, swizzled reads — round-7 pair)
        f16x8 pa[2][2];
        #pragma unroll
        for (int mt = 0; mt < 2; ++mt)
            #pragma unroll
            for (int cc = 0; cc < 2; ++cc) {
                int rowp = wave * 32 + mt * 16 + r;
                int bks = (cc * 4 + quad) ^ (((r >> 2) & 3) << 1);
                pa[mt][cc] = *(const f16x8*)(p_s + rowp * 64 + bks * 8);
            }

        // PV with V^T b-frags (chunk-swizzled reads — round-7 pair)
        #pragma unroll
        for (int dt = 0; dt < 5; ++dt)
            #pragma unroll
            for (int cc = 0; cc < 2; ++cc) {
                int ck = (cc * 4 + quad) ^ (r & 7);
                f16x8 vbf = *(const f16x8*)(v_s + (dt * 16 + r) * 64 + ck * 8);
                oacc[0][dt] = __builtin_amdgcn_mfma_f32_16x16x32_f16(pa[0][cc], vbf, oacc[0][dt], 0, 0, 0);
                oacc[1][dt] = __builtin_amdgcn_mfma_f32_16x16x32_f16(pa[1][cc], vbf, oacc[1][dt], 0, 0, 0);
            }
    }

    // deferred l reduction (across the 16 r-lanes of each quad)
    float inv_l[2][4];
    #pragma unroll
    for (int mt = 0; mt < 2; ++mt)
        #pragma unroll
        for (int v = 0; v < 4; ++v) {
            float l = l_part[mt][v];
            l += __shfl_xor(l, 1);
            l += __shfl_xor(l, 2);
            l += __shfl_xor(l, 4);
            l += __shfl_xor(l, 8);
            inv_l[mt][v] = 1.0f / l;
        }

    // epilogue: normalize + fp16-split into LDS [128][80] hi/lo, uint4 stores
    __syncthreads();
    #pragma unroll
    for (int mt = 0; mt < 2; ++mt)
        #pragma unroll
        for (int v = 0; v < 4; ++v) {
            int row = wave * 32 + mt * 16 + quad * 4 + v;
            #pragma unroll
            for (int dt = 0; dt < 5; ++dt) {
                float o = oacc[mt][dt][v] * inv_l[mt][v];
                ushort hh, ll;
                splitf16(o, hh, ll);
                lds[row * 80 + dt * 16 + r] = hh;
                lds[10240 + row * 80 + dt * 16 + r] = ll;
            }
        }
    __syncthreads();
    {
        size_t gbase = ((size_t)b * NN + q0) * HIDDEN + h * HD;
        #pragma unroll
        for (int i = 0; i < 10; ++i) {
            int u = tid + i * 256;            // 0..2559
            int plane = u / 1280, idx = u % 1280;
            int row = idx / 10, part = idx % 10;
            uint4 w = *(const uint4*)(lds + plane * 10240 + idx * 8);
            ushort* dst = (plane ? ao_lo : ao_hi) + gbase + (size_t)row * HIDDEN + part * 8;
            *(uint4*)dst = w;
        }
    }
}

// ---------------------------------------------------------------------------
extern "C" void kernel_launch(void* const* d_in, const int* in_sizes, int n_in,
                              void* d_out, int out_size, void* d_ws, size_t ws_size,
                              hipStream_t stream)
{
    const float* x      = (const float*)d_in[0];
    const float* cos_t  = (const float*)d_in[1];
    const float* sin_t  = (const float*)d_in[2];
    const float* qkv_w  = (const float*)d_in[3];
    const float* qkv_b  = (const float*)d_in[4];
    const float* proj_w = (const float*)d_in[5];
    const float* proj_b = (const float*)d_in[6];
    float* out = (float*)d_out;

    char* ws = (char*)d_ws;
    // layout (bytes), phase-based reuse:
    //   [0, 62914560)           qkv fp32 (gemm1 out; dead after rope_split)
    //       -> ao_hi @0 (10485760), ao_lo @10485760 (attn out, fp16 hi/lo)
    //   [62914560, 72744960)    wT fp16 (qkv_w^T); after gemm1:
    //       -> vt fp16 @62914560 (10485760, ends 73400320)
    //       -> re-written by tsplit_f16(proj_w) AFTER attention (3276800)
    //   [82575360, 103546880)   x split fp16 hi/lo (gemm1 A); after gemm1:
    //       -> qf @83886080 (12582912), kf @96468992 (ends 109051904)
    float*  qkv   = (float*)ws;
    ushort* ao_hi = (ushort*)ws;
    ushort* ao_lo = (ushort*)(ws + 10485760);
    ushort* wT    = (ushort*)(ws + 62914560);
    ushort* vt    = (ushort*)(ws + 62914560);
    ushort* a_hi  = (ushort*)(ws + 82575360);
    ushort* a_lo  = (ushort*)(ws + 93061120);
    ushort* q_f   = (ushort*)(ws + 83886080);
    ushort* k_f   = (ushort*)(ws + 96468992);

    // 1) split x into fp16 hi/lo
    split_f16_kernel<<<(MROWS * HIDDEN / 4 + 255) / 256, 256, 0, stream>>>(
        x, a_hi, a_lo, MROWS * HIDDEN / 4);

    // 2) transpose qkv_w -> fp16
    tsplit_f16_kernel<<<dim3(3 * HIDDEN / 32, HIDDEN / 32), 256, 0, stream>>>(
        qkv_w, wT, HIDDEN, 3 * HIDDEN);

    // 3) qkv = x @ qkv_w + qkv_b   (fp16x2 MFMA)
    gemm_f16x2_kernel<<<dim3(3 * HIDDEN / BN, MROWS / BM), 256, 0, stream>>>(
        a_hi, a_lo, wT, qkv_b, qkv, MROWS, 3 * HIDDEN, HIDDEN);

    // 4) RoPE + fp16 relayout (overwrites wT and x-split regions — both dead)
    rope_split_kernel<<<dim3(NN / 64, HEADS, BB), 256, 0, stream>>>(
        qkv, cos_t, sin_t, q_f, k_f, vt);

    // 5) MFMA flash attention (ao overwrites qkv region — dead now)
    attn_mfma_kernel<<<dim3(NN / 128, HEADS, BB), 256, 0, stream>>>(
        q_f, k_f, vt, ao_hi, ao_lo);

    // 6) transpose proj_w -> fp16 (overwrites vt region — dead after attn)
    tsplit_f16_kernel<<<dim3(HIDDEN / 32, HIDDEN / 32), 256, 0, stream>>>(
        proj_w, wT, HIDDEN, HIDDEN);

    // 7) out = attn_out @ proj_w + proj_b   (fp16x2 MFMA)
    gemm_f16x2_kernel<<<dim3(HIDDEN / BN, MROWS / BM), 256, 0, stream>>>(
        ao_hi, ao_lo, wT, proj_b, out, MROWS, HIDDEN, HIDDEN);
}